// Round 6
// baseline (1186.716 us; speedup 1.0000x reference)
//
#include <hip/hip_runtime.h>
#include <hip/hip_bf16.h>

// GAT 3-layer: N=50000 nodes, E=800000 edges, H=6 heads.
// CSR-by-dst built per call; dst-centric atomic-free aggregation.
// R1: transforms = tiled f32 GEMMs (W re-read was L2-BW bound at 577us).
// R2: dst-centric edge softmax over CSR (zero atomics), alpha in CSR order.
// R3: h stored bf16 (aggregate was fetch-BW bound); f32 accumulate everywhere.
// R4: layers 2/3 GEMM = 128x128 tile, 8x8 split micro-tile, fused attn epilogue.
// R5: gemm_attn register-double-buffered (barrier stall was 50% of cycles),
//     parallel 3-phase CSR scan, edge_softmax pass2 reads cached logits.

#define HHEADS 6

__device__ __forceinline__ float bfl(unsigned u) { return __uint_as_float(u << 16); }
__device__ __forceinline__ float bfh(unsigned u) { return __uint_as_float(u & 0xffff0000u); }

// ---------------- CSR build ----------------
__global__ void hist_kernel(const int* __restrict__ dst, int* __restrict__ count, int E) {
    int e = blockIdx.x * blockDim.x + threadIdx.x;
    if (e >= E) return;
    atomicAdd(&count[dst[e]], 1);
}

// phase A: per-1024-block exclusive scan + block totals
__global__ void scan_block(const int* __restrict__ count, int* __restrict__ offsets,
                           int* __restrict__ bsum, int n) {
    __shared__ int s[1024];
    int i = blockIdx.x * 1024 + threadIdx.x;
    int v = (i < n) ? count[i] : 0;
    s[threadIdx.x] = v;
    __syncthreads();
    for (int off = 1; off < 1024; off <<= 1) {
        int t = (threadIdx.x >= (unsigned)off) ? s[threadIdx.x - off] : 0;
        __syncthreads();
        s[threadIdx.x] += t;
        __syncthreads();
    }
    if (i < n) offsets[i] = s[threadIdx.x] - v;
    if (threadIdx.x == 1023) bsum[blockIdx.x] = s[1023];
}

// phase B: single block scans block totals (nb <= 64)
__global__ void scan_tops(int* __restrict__ bsum, int nb) {
    __shared__ int s[64];
    int t = threadIdx.x;  // blockDim = 64
    int v = (t < nb) ? bsum[t] : 0;
    s[t] = v;
    __syncthreads();
    for (int off = 1; off < 64; off <<= 1) {
        int tmp = (t >= off) ? s[t - off] : 0;
        __syncthreads();
        s[t] += tmp;
        __syncthreads();
    }
    if (t < nb) bsum[t] = s[t] - v;  // exclusive
}

// phase C: add block offsets; write sentinel
__global__ void scan_add(int* __restrict__ offsets, const int* __restrict__ bsum, int n,
                         int total) {
    int i = blockIdx.x * 1024 + threadIdx.x;
    if (i < n) offsets[i] += bsum[blockIdx.x];
    if (i == 0) offsets[n] = total;
}

__global__ void scatter_kernel(const int* __restrict__ src, const int* __restrict__ dst,
                               const int* __restrict__ offsets, int* __restrict__ cursor,
                               int* __restrict__ ssrc, int E) {
    int e = blockIdx.x * blockDim.x + threadIdx.x;
    if (e >= E) return;
    int d = dst[e];
    int pos = offsets[d] + atomicAdd(&cursor[d], 1);
    ssrc[pos] = src[e];
}

// ---------------- weight repack: Wp[k*HF + hd*F + f] = W[hd,k,f] ----------------
__global__ void repack_w(const float* __restrict__ W, float* __restrict__ Wp, int FIN, int F) {
    int HF = HHEADS * F;
    int i = blockIdx.x * blockDim.x + threadIdx.x;
    if (i >= FIN * HF) return;
    int k = i / HF, c = i % HF;
    int hd = c / F, f = c % F;
    Wp[i] = W[(hd * FIN + k) * F + f];
}

// ---------------- small GEMM (layer 1, K=11): 64x64, 4x4 micro-tile ----------------
template <int BM, int BN, int BK>
__global__ __launch_bounds__(256) void gemm_small(const float* __restrict__ A,
                                                  const float* __restrict__ B,
                                                  __hip_bfloat16* __restrict__ C, int M,
                                                  int K, int N) {
    __shared__ float As[BK][BM + 4];
    __shared__ float Bs[BK][BN];
    int tid = threadIdx.x;
    int tx = tid % 16, ty = tid / 16;
    int m0 = blockIdx.y * BM, n0 = blockIdx.x * BN;
    float acc[4][4] = {};
    for (int kk0 = 0; kk0 < K; kk0 += BK) {
#pragma unroll
        for (int i = 0; i < (BM * BK) / 256; ++i) {
            int idx = tid + i * 256;
            int m = idx / BK, k = idx % BK;
            float v = 0.f;
            if (m0 + m < M && kk0 + k < K) v = A[(size_t)(m0 + m) * K + kk0 + k];
            As[k][m] = v;
        }
#pragma unroll
        for (int i = 0; i < (BK * BN) / 1024; ++i) {
            int idx = tid + i * 256;
            int k = idx / (BN / 4), n4 = idx % (BN / 4);
            float4 v = make_float4(0.f, 0.f, 0.f, 0.f);
            if (kk0 + k < K && n0 + n4 * 4 < N)
                v = *(const float4*)&B[(size_t)(kk0 + k) * N + n0 + n4 * 4];
            *(float4*)&Bs[k][n4 * 4] = v;
        }
        __syncthreads();
#pragma unroll
        for (int k = 0; k < BK; ++k) {
            float4 av = *(const float4*)&As[k][ty * 4];
            float4 bv = *(const float4*)&Bs[k][tx * 4];
            float a[4] = {av.x, av.y, av.z, av.w};
            float b[4] = {bv.x, bv.y, bv.z, bv.w};
#pragma unroll
            for (int i = 0; i < 4; ++i)
#pragma unroll
                for (int j = 0; j < 4; ++j) acc[i][j] += a[i] * b[j];
        }
        __syncthreads();
    }
#pragma unroll
    for (int i = 0; i < 4; ++i) {
        int m = m0 + ty * 4 + i;
        if (m < M && n0 + tx * 4 < N) {
            __hip_bfloat16 tmp[4];
#pragma unroll
            for (int j = 0; j < 4; ++j) tmp[j] = __float2bfloat16(acc[i][j]);
            *(uint2*)&C[(size_t)m * N + n0 + tx * 4] = *(uint2*)tmp;
        }
    }
}

// es[n,hd] for layer 1; block = HF threads, one node per block.
template <int F>
__global__ void attn_terms(const __hip_bfloat16* __restrict__ h, const float* __restrict__ as_,
                           const float* __restrict__ ad_, float* __restrict__ es,
                           float* __restrict__ ed) {
    constexpr int HF = HHEADS * F;
    int node = blockIdx.x;
    int t = threadIdx.x;
    float v = __bfloat162float(h[(size_t)node * HF + t]);
    float s = v * as_[t];
    float d = v * ad_[t];
#pragma unroll
    for (int off = F / 2; off > 0; off >>= 1) {
        s += __shfl_down(s, off, F);
        d += __shfl_down(d, off, F);
    }
    if ((t & (F - 1)) == 0) {
        int hd = t / F;
        es[node * HHEADS + hd] = s;
        ed[node * HHEADS + hd] = d;
    }
}

// ---------------- big GEMM + fused attn (layers 2/3) ----------------
// C[M,N] = A[M,K] @ B[K,N], C bf16; es/ed from f32 acc in epilogue.
// BM=BN=128, BK=16, 256 threads, 8x8 micro-tile as 2x2 split 4x4 blocks.
// Register double-buffer: prefetch tile t+1 during compute of tile t.
// Requires: K % 16 == 0, N % 64 == 0, F in {32,64}.
template <int F>
__global__ __launch_bounds__(256, 4) void gemm_attn(const float* __restrict__ A,
                                                    const float* __restrict__ B,
                                                    __hip_bfloat16* __restrict__ C,
                                                    const float* __restrict__ as_,
                                                    const float* __restrict__ ad_,
                                                    float* __restrict__ es,
                                                    float* __restrict__ ed, int M, int K,
                                                    int N) {
    constexpr int BM = 128, BN = 128, BK = 16;
    __shared__ float As[BK][BM + 4];  // stride 132: staging writes 2-way (free)
    __shared__ float Bs[BK][BN];
    int tid = threadIdx.x;
    int tx = tid % 16, ty = tid / 16;
    int m0 = blockIdx.y * BM, n0 = blockIdx.x * BN;

    float4 aReg[2], bReg[2];
    auto prefetch = [&](int kk0) {
#pragma unroll
        for (int i = 0; i < 2; ++i) {
            int idx = tid + i * 256;
            int m = idx >> 2, k4 = idx & 3;
            int gm = m0 + m;
            aReg[i] = make_float4(0.f, 0.f, 0.f, 0.f);
            if (gm < M) aReg[i] = *(const float4*)&A[(size_t)gm * K + kk0 + k4 * 4];
            int bk = idx >> 5, n4 = idx & 31;
            bReg[i] = make_float4(0.f, 0.f, 0.f, 0.f);
            if (n0 + n4 * 4 < N) bReg[i] = *(const float4*)&B[(size_t)(kk0 + bk) * N + n0 + n4 * 4];
        }
    };

    prefetch(0);
    float acc[2][2][4][4] = {};  // [ri][ci][i][j]
    const int nk = K / BK;
    for (int t = 0; t < nk; ++t) {
        __syncthreads();  // previous compute done; LDS safe to overwrite
#pragma unroll
        for (int i = 0; i < 2; ++i) {
            int idx = tid + i * 256;
            int m = idx >> 2, k4 = idx & 3;
            As[k4 * 4 + 0][m] = aReg[i].x;
            As[k4 * 4 + 1][m] = aReg[i].y;
            As[k4 * 4 + 2][m] = aReg[i].z;
            As[k4 * 4 + 3][m] = aReg[i].w;
            int bk = idx >> 5, n4 = idx & 31;
            *(float4*)&Bs[bk][n4 * 4] = bReg[i];
        }
        __syncthreads();  // LDS visible
        if (t + 1 < nk) prefetch((t + 1) * BK);  // loads fly during compute
#pragma unroll
        for (int k = 0; k < BK; ++k) {
            float4 a0 = *(const float4*)&As[k][ty * 4];
            float4 a1 = *(const float4*)&As[k][64 + ty * 4];
            float4 b0 = *(const float4*)&Bs[k][tx * 4];
            float4 b1 = *(const float4*)&Bs[k][64 + tx * 4];
            float a[2][4] = {{a0.x, a0.y, a0.z, a0.w}, {a1.x, a1.y, a1.z, a1.w}};
            float b[2][4] = {{b0.x, b0.y, b0.z, b0.w}, {b1.x, b1.y, b1.z, b1.w}};
#pragma unroll
            for (int ri = 0; ri < 2; ++ri)
#pragma unroll
                for (int ci = 0; ci < 2; ++ci)
#pragma unroll
                    for (int i = 0; i < 4; ++i)
#pragma unroll
                        for (int j = 0; j < 4; ++j) acc[ri][ci][i][j] += a[ri][i] * b[ci][j];
        }
    }
    // attention vectors for this thread's 8 columns
    float asv[2][4], adv[2][4];
#pragma unroll
    for (int ci = 0; ci < 2; ++ci)
#pragma unroll
        for (int j = 0; j < 4; ++j) {
            int c = n0 + ci * 64 + tx * 4 + j;
            asv[ci][j] = (c < N) ? as_[c] : 0.f;
            adv[ci][j] = (c < N) ? ad_[c] : 0.f;
        }
    constexpr int W = F / 4;  // lanes per head segment (8 or 16)
#pragma unroll
    for (int ri = 0; ri < 2; ++ri)
#pragma unroll
        for (int i = 0; i < 4; ++i) {
            int gm = m0 + ri * 64 + ty * 4 + i;
            bool rowok = gm < M;
#pragma unroll
            for (int ci = 0; ci < 2; ++ci) {
                int c0 = n0 + ci * 64 + tx * 4;
                if (c0 < N) {  // uniform per ci (N % 64 == 0)
                    if (rowok) {
                        __hip_bfloat16 tmp[4];
#pragma unroll
                        for (int j = 0; j < 4; ++j) tmp[j] = __float2bfloat16(acc[ri][ci][i][j]);
                        *(uint2*)&C[(size_t)gm * N + c0] = *(uint2*)tmp;
                    }
                    float ps = 0.f, pd = 0.f;
#pragma unroll
                    for (int j = 0; j < 4; ++j) {
                        ps += acc[ri][ci][i][j] * asv[ci][j];
                        pd += acc[ri][ci][i][j] * adv[ci][j];
                    }
#pragma unroll
                    for (int off = W / 2; off > 0; off >>= 1) {
                        ps += __shfl_down(ps, off, W);
                        pd += __shfl_down(pd, off, W);
                    }
                    if (rowok && (tx & (W - 1)) == 0) {
                        int hd = c0 / F;
                        es[(size_t)gm * HHEADS + hd] = ps;
                        ed[(size_t)gm * HHEADS + hd] = pd;
                    }
                }
            }
        }
}

// ---------------- edge softmax: dst-centric, atomic-free ----------------
// Pass 1 gathers es (random), caches leaky-relu logits in alpha (sequential);
// pass 2 re-reads alpha sequentially -> exp -> rewrite, sum.
__global__ void edge_softmax(const float* __restrict__ es, const float* __restrict__ ed,
                             const int* __restrict__ offsets, const int* __restrict__ ssrc,
                             float* __restrict__ alpha, float* __restrict__ denom, int n) {
    int i = blockIdx.x * blockDim.x + threadIdx.x;
    if (i >= n * HHEADS) return;
    int node = i / HHEADS, hd = i % HHEADS;
    int a = offsets[node], b = offsets[node + 1];
    float edv = ed[i];
    float m = -1e30f;
    for (int j = a; j < b; ++j) {
        float v = es[ssrc[j] * HHEADS + hd] + edv;
        v = v > 0.f ? v : 0.2f * v;  // leaky relu 0.2
        alpha[(size_t)j * HHEADS + hd] = v;
        m = fmaxf(m, v);
    }
    float sum = 0.f;
    for (int j = a; j < b; ++j) {
        float ex = expf(alpha[(size_t)j * HHEADS + hd] - m);
        alpha[(size_t)j * HHEADS + hd] = ex;
        sum += ex;
    }
    denom[i] = sum;
}

// thread per (node, 8-channel group); 16B uint4 gathers of bf16 h[src].
template <int F>
__global__ void aggregate_kernel(const __hip_bfloat16* __restrict__ h,
                                 const float* __restrict__ alpha,
                                 const float* __restrict__ denom,
                                 const int* __restrict__ offsets, const int* __restrict__ ssrc,
                                 float* __restrict__ out, int n) {
    constexpr int HF = HHEADS * F;
    constexpr int C8 = HF / 8;
    int tid = blockIdx.x * blockDim.x + threadIdx.x;
    if (tid >= n * C8) return;
    int node = tid / C8, q = tid % C8;
    int c = q * 8, hd = c / F;
    int a = offsets[node], b = offsets[node + 1];
    float acc[8] = {};
    for (int j = a; j < b; ++j) {
        int s = ssrc[j];
        float al = alpha[(size_t)j * HHEADS + hd];
        uint4 hv = *(const uint4*)&h[(size_t)s * HF + c];
        acc[0] += al * bfl(hv.x);
        acc[1] += al * bfh(hv.x);
        acc[2] += al * bfl(hv.y);
        acc[3] += al * bfh(hv.y);
        acc[4] += al * bfl(hv.z);
        acc[5] += al * bfh(hv.z);
        acc[6] += al * bfl(hv.w);
        acc[7] += al * bfh(hv.w);
    }
    float invd = 1.0f / (denom[node * HHEADS + hd] + 1e-16f);
    float4 o0, o1;
    float* op = &o0.x;
#pragma unroll
    for (int k = 0; k < 8; ++k) {
        float v = acc[k] * invd;
        v = v > 0.f ? v : (expf(v) - 1.0f);  // elu
        op[k] = v;
    }
    *(float4*)&out[(size_t)node * HF + c] = o0;
    *(float4*)&out[(size_t)node * HF + c + 4] = o1;
}

// ---------------- pooling + head ----------------
__global__ void pool_kernel(const float* __restrict__ out3, float* __restrict__ g, int n) {
    int b = blockIdx.x, t = threadIdx.x;
    int chunk = (n + gridDim.x - 1) / gridDim.x;
    int n0 = b * chunk, n1 = min(n, n0 + chunk);
    float a0 = 0.f, a1 = 0.f;
    for (int node = n0; node < n1; ++node) {
        a0 += out3[(size_t)node * 384 + t];
        if (t < 128) a1 += out3[(size_t)node * 384 + 256 + t];
    }
    atomicAdd(&g[t], a0);
    if (t < 128) atomicAdd(&g[256 + t], a1);
}

__global__ void final_kernel(const float* __restrict__ g, const float* __restrict__ Wd,
                             const float* __restrict__ bd, float* __restrict__ outp) {
    __shared__ float red[384];
    int t = threadIdx.x;  // blockDim = 384
    float v = g[t];
    red[t] = v * v;
    __syncthreads();
    for (int s = 192; s >= 3; s >>= 1) {
        if (t < s) red[t] += red[t + s];
        __syncthreads();
    }
    __shared__ float scale_s;
    if (t == 0) {
        float norm = sqrtf(red[0] + red[1] + red[2]);
        scale_s = 1.0f / fmaxf(norm, 1e-12f);
    }
    __syncthreads();
    float scale = scale_s;
    red[t] = v * scale * Wd[t];
    __syncthreads();
    for (int s = 192; s >= 3; s >>= 1) {
        if (t < s) red[t] += red[t + s];
        __syncthreads();
    }
    if (t == 0) outp[0] = red[0] + red[1] + red[2] + bd[0];
}

// ---------------- host side ----------------
template <int F>
static void run_edges_and_agg(__hip_bfloat16* hbuf, float* outbuf, float* es, float* ed,
                              float* denom, float* alpha, const int* offsets, const int* ssrc,
                              int N, int E, hipStream_t stream) {
    constexpr int HF = HHEADS * F;
    edge_softmax<<<(N * HHEADS + 255) / 256, 256, 0, stream>>>(es, ed, offsets, ssrc, alpha,
                                                               denom, N);
    long total = (long)N * HF / 8;
    aggregate_kernel<F><<<(total + 255) / 256, 256, 0, stream>>>(hbuf, alpha, denom, offsets,
                                                                 ssrc, outbuf, N);
}

extern "C" void kernel_launch(void* const* d_in, const int* in_sizes, int n_in, void* d_out,
                              int out_size, void* d_ws, size_t ws_size, hipStream_t stream) {
    const float* x = (const float*)d_in[0];
    const int* ei = (const int*)d_in[1];
    const float* W1 = (const float*)d_in[2];
    const float* a1s = (const float*)d_in[3];
    const float* a1d = (const float*)d_in[4];
    const float* W2 = (const float*)d_in[5];
    const float* a2s = (const float*)d_in[6];
    const float* a2d = (const float*)d_in[7];
    const float* W3 = (const float*)d_in[8];
    const float* a3s = (const float*)d_in[9];
    const float* a3d = (const float*)d_in[10];
    const float* Wd = (const float*)d_in[11];
    const float* bd = (const float*)d_in[12];
    float* outp = (float*)d_out;

    const int N = in_sizes[0] / 11;
    const int E = in_sizes[1] / 2;
    const int* src = ei;
    const int* dst = ei + E;

    char* w = (char*)d_ws;
    size_t off = 0;
    auto A = [&](size_t bytes) {
        size_t o = off;
        off += (bytes + 255) & ~(size_t)255;
        return o;
    };
    __hip_bfloat16* bufH = (__hip_bfloat16*)(w + A((size_t)N * 384 * 2));  // bf16 h
    float* bufA = (float*)(w + A((size_t)N * 384 * 4));  // layer1 out (96), layer3 out (384)
    float* bufB = (float*)(w + A((size_t)N * 192 * 4));  // layer2 out
    float* es = (float*)(w + A((size_t)N * HHEADS * 4));
    float* ed = (float*)(w + A((size_t)N * HHEADS * 4));
    float* denom = (float*)(w + A((size_t)N * HHEADS * 4));
    float* alpha = (float*)(w + A((size_t)E * HHEADS * 4));
    float* wp = (float*)(w + A((size_t)192 * 384 * 4));  // repacked W, max layer3
    int* count = (int*)(w + A((size_t)(N + 1) * 4));
    int* cursor = (int*)(w + A((size_t)(N + 1) * 4));
    int* offsets = (int*)(w + A((size_t)(N + 1) * 4));
    int* bsum = (int*)(w + A(64 * 4));
    int* ssrc = (int*)(w + A((size_t)E * 4));
    float* g = (float*)(w + A(384 * 4));

    // CSR build (by dst)
    hipMemsetAsync(count, 0, (size_t)N * 4, stream);
    hipMemsetAsync(cursor, 0, (size_t)N * 4, stream);
    hist_kernel<<<(E + 255) / 256, 256, 0, stream>>>(dst, count, E);
    int nb = (N + 1023) / 1024;  // 49 <= 64
    scan_block<<<nb, 1024, 0, stream>>>(count, offsets, bsum, N);
    scan_tops<<<1, 64, 0, stream>>>(bsum, nb);
    scan_add<<<nb, 1024, 0, stream>>>(offsets, bsum, N, E);
    scatter_kernel<<<(E + 255) / 256, 256, 0, stream>>>(src, dst, offsets, cursor, ssrc, E);

    // ---- layer 1 (FIN=11, F=16) ----
    repack_w<<<(11 * 96 + 255) / 256, 256, 0, stream>>>(W1, wp, 11, 16);
    {
        dim3 grid((96 + 63) / 64, (N + 63) / 64);
        gemm_small<64, 64, 32><<<grid, 256, 0, stream>>>(x, wp, bufH, N, 11, 96);
    }
    attn_terms<16><<<N, 96, 0, stream>>>(bufH, a1s, a1d, es, ed);
    run_edges_and_agg<16>(bufH, bufA, es, ed, denom, alpha, offsets, ssrc, N, E, stream);

    // ---- layer 2 (FIN=96, F=32) ----
    repack_w<<<(96 * 192 + 255) / 256, 256, 0, stream>>>(W2, wp, 96, 32);
    {
        dim3 grid((192 + 127) / 128, (N + 127) / 128);
        gemm_attn<32><<<grid, 256, 0, stream>>>(bufA, wp, bufH, a2s, a2d, es, ed, N, 96, 192);
    }
    run_edges_and_agg<32>(bufH, bufB, es, ed, denom, alpha, offsets, ssrc, N, E, stream);

    // ---- layer 3 (FIN=192, F=64) ----
    repack_w<<<(192 * 384 + 255) / 256, 256, 0, stream>>>(W3, wp, 192, 64);
    {
        dim3 grid((384 + 127) / 128, (N + 127) / 128);
        gemm_attn<64><<<grid, 256, 0, stream>>>(bufB, wp, bufH, a3s, a3d, es, ed, N, 192, 384);
    }
    run_edges_and_agg<64>(bufH, bufA, es, ed, denom, alpha, offsets, ssrc, N, E, stream);

    // sum-pool -> normalize -> dense
    hipMemsetAsync(g, 0, 384 * 4, stream);
    pool_kernel<<<256, 256, 0, stream>>>(bufA, g, N);
    final_kernel<<<1, 384, 0, stream>>>(g, Wd, bd, outp);
}

// Round 7
// 729.939 us; speedup vs baseline: 1.6258x; 1.6258x over previous
//
#include <hip/hip_runtime.h>
#include <hip/hip_bf16.h>

// GAT 3-layer: N=50000 nodes, E=800000 edges, H=6 heads.
// CSR-by-dst built per call; dst-centric atomic-free aggregation.
// R1: transforms = tiled f32 GEMMs (W re-read was L2-BW bound at 577us).
// R2: dst-centric edge softmax over CSR (zero atomics), alpha in CSR order.
// R3: h stored bf16 (aggregate was fetch-BW bound); f32 accumulate everywhere.
// R4: layers 2/3 GEMM = 128x128 tile, 8x8 split micro-tile, fused attn epilogue.
// R5: gemm_attn register-double-buffer; parallel 3-phase CSR scan; edge_softmax
//     pass2 reads cached logits.
// R6: FIX R5 spill: __launch_bounds__(256,4) had forced VGPR 92->64, acc
//     spilled to scratch (WRITE_SIZE 44MB->1GB). No min-waves pin now.

#define HHEADS 6

__device__ __forceinline__ float bfl(unsigned u) { return __uint_as_float(u << 16); }
__device__ __forceinline__ float bfh(unsigned u) { return __uint_as_float(u & 0xffff0000u); }

// ---------------- CSR build ----------------
__global__ void hist_kernel(const int* __restrict__ dst, int* __restrict__ count, int E) {
    int e = blockIdx.x * blockDim.x + threadIdx.x;
    if (e >= E) return;
    atomicAdd(&count[dst[e]], 1);
}

// phase A: per-1024-block exclusive scan + block totals
__global__ void scan_block(const int* __restrict__ count, int* __restrict__ offsets,
                           int* __restrict__ bsum, int n) {
    __shared__ int s[1024];
    int i = blockIdx.x * 1024 + threadIdx.x;
    int v = (i < n) ? count[i] : 0;
    s[threadIdx.x] = v;
    __syncthreads();
    for (int off = 1; off < 1024; off <<= 1) {
        int t = (threadIdx.x >= (unsigned)off) ? s[threadIdx.x - off] : 0;
        __syncthreads();
        s[threadIdx.x] += t;
        __syncthreads();
    }
    if (i < n) offsets[i] = s[threadIdx.x] - v;
    if (threadIdx.x == 1023) bsum[blockIdx.x] = s[1023];
}

// phase B: single block scans block totals (nb <= 64)
__global__ void scan_tops(int* __restrict__ bsum, int nb) {
    __shared__ int s[64];
    int t = threadIdx.x;  // blockDim = 64
    int v = (t < nb) ? bsum[t] : 0;
    s[t] = v;
    __syncthreads();
    for (int off = 1; off < 64; off <<= 1) {
        int tmp = (t >= off) ? s[t - off] : 0;
        __syncthreads();
        s[t] += tmp;
        __syncthreads();
    }
    if (t < nb) bsum[t] = s[t] - v;  // exclusive
}

// phase C: add block offsets; write sentinel
__global__ void scan_add(int* __restrict__ offsets, const int* __restrict__ bsum, int n,
                         int total) {
    int i = blockIdx.x * 1024 + threadIdx.x;
    if (i < n) offsets[i] += bsum[blockIdx.x];
    if (i == 0) offsets[n] = total;
}

__global__ void scatter_kernel(const int* __restrict__ src, const int* __restrict__ dst,
                               const int* __restrict__ offsets, int* __restrict__ cursor,
                               int* __restrict__ ssrc, int E) {
    int e = blockIdx.x * blockDim.x + threadIdx.x;
    if (e >= E) return;
    int d = dst[e];
    int pos = offsets[d] + atomicAdd(&cursor[d], 1);
    ssrc[pos] = src[e];
}

// ---------------- weight repack: Wp[k*HF + hd*F + f] = W[hd,k,f] ----------------
__global__ void repack_w(const float* __restrict__ W, float* __restrict__ Wp, int FIN, int F) {
    int HF = HHEADS * F;
    int i = blockIdx.x * blockDim.x + threadIdx.x;
    if (i >= FIN * HF) return;
    int k = i / HF, c = i % HF;
    int hd = c / F, f = c % F;
    Wp[i] = W[(hd * FIN + k) * F + f];
}

// ---------------- small GEMM (layer 1, K=11): 64x64, 4x4 micro-tile ----------------
template <int BM, int BN, int BK>
__global__ __launch_bounds__(256) void gemm_small(const float* __restrict__ A,
                                                  const float* __restrict__ B,
                                                  __hip_bfloat16* __restrict__ C, int M,
                                                  int K, int N) {
    __shared__ float As[BK][BM + 4];
    __shared__ float Bs[BK][BN];
    int tid = threadIdx.x;
    int tx = tid % 16, ty = tid / 16;
    int m0 = blockIdx.y * BM, n0 = blockIdx.x * BN;
    float acc[4][4] = {};
    for (int kk0 = 0; kk0 < K; kk0 += BK) {
#pragma unroll
        for (int i = 0; i < (BM * BK) / 256; ++i) {
            int idx = tid + i * 256;
            int m = idx / BK, k = idx % BK;
            float v = 0.f;
            if (m0 + m < M && kk0 + k < K) v = A[(size_t)(m0 + m) * K + kk0 + k];
            As[k][m] = v;
        }
#pragma unroll
        for (int i = 0; i < (BK * BN) / 1024; ++i) {
            int idx = tid + i * 256;
            int k = idx / (BN / 4), n4 = idx % (BN / 4);
            float4 v = make_float4(0.f, 0.f, 0.f, 0.f);
            if (kk0 + k < K && n0 + n4 * 4 < N)
                v = *(const float4*)&B[(size_t)(kk0 + k) * N + n0 + n4 * 4];
            *(float4*)&Bs[k][n4 * 4] = v;
        }
        __syncthreads();
#pragma unroll
        for (int k = 0; k < BK; ++k) {
            float4 av = *(const float4*)&As[k][ty * 4];
            float4 bv = *(const float4*)&Bs[k][tx * 4];
            float a[4] = {av.x, av.y, av.z, av.w};
            float b[4] = {bv.x, bv.y, bv.z, bv.w};
#pragma unroll
            for (int i = 0; i < 4; ++i)
#pragma unroll
                for (int j = 0; j < 4; ++j) acc[i][j] += a[i] * b[j];
        }
        __syncthreads();
    }
#pragma unroll
    for (int i = 0; i < 4; ++i) {
        int m = m0 + ty * 4 + i;
        if (m < M && n0 + tx * 4 < N) {
            __hip_bfloat16 tmp[4];
#pragma unroll
            for (int j = 0; j < 4; ++j) tmp[j] = __float2bfloat16(acc[i][j]);
            *(uint2*)&C[(size_t)m * N + n0 + tx * 4] = *(uint2*)tmp;
        }
    }
}

// es[n,hd] for layer 1; block = HF threads, one node per block.
template <int F>
__global__ void attn_terms(const __hip_bfloat16* __restrict__ h, const float* __restrict__ as_,
                           const float* __restrict__ ad_, float* __restrict__ es,
                           float* __restrict__ ed) {
    constexpr int HF = HHEADS * F;
    int node = blockIdx.x;
    int t = threadIdx.x;
    float v = __bfloat162float(h[(size_t)node * HF + t]);
    float s = v * as_[t];
    float d = v * ad_[t];
#pragma unroll
    for (int off = F / 2; off > 0; off >>= 1) {
        s += __shfl_down(s, off, F);
        d += __shfl_down(d, off, F);
    }
    if ((t & (F - 1)) == 0) {
        int hd = t / F;
        es[node * HHEADS + hd] = s;
        ed[node * HHEADS + hd] = d;
    }
}

// ---------------- big GEMM + fused attn (layers 2/3) ----------------
// C[M,N] = A[M,K] @ B[K,N], C bf16; es/ed from f32 acc in epilogue.
// BM=BN=128, BK=16, 256 threads, 8x8 micro-tile as 2x2 split 4x4 blocks.
// Register double-buffer: prefetch tile t+1 during compute of tile t.
// NOTE: no min-waves in launch_bounds — (256,4) forced 64 VGPR and spilled
// the 64-reg accumulator to scratch (R5: WRITE_SIZE 44MB -> 1GB).
// Requires: K % 16 == 0, N % 64 == 0, F in {32,64}.
template <int F>
__global__ __launch_bounds__(256) void gemm_attn(const float* __restrict__ A,
                                                 const float* __restrict__ B,
                                                 __hip_bfloat16* __restrict__ C,
                                                 const float* __restrict__ as_,
                                                 const float* __restrict__ ad_,
                                                 float* __restrict__ es,
                                                 float* __restrict__ ed, int M, int K,
                                                 int N) {
    constexpr int BM = 128, BN = 128, BK = 16;
    __shared__ float As[BK][BM + 4];  // stride 132: staging writes 2-way (free)
    __shared__ float Bs[BK][BN];
    int tid = threadIdx.x;
    int tx = tid % 16, ty = tid / 16;
    int m0 = blockIdx.y * BM, n0 = blockIdx.x * BN;

    float4 aReg[2], bReg[2];
    auto prefetch = [&](int kk0) {
#pragma unroll
        for (int i = 0; i < 2; ++i) {
            int idx = tid + i * 256;
            int m = idx >> 2, k4 = idx & 3;
            int gm = m0 + m;
            aReg[i] = make_float4(0.f, 0.f, 0.f, 0.f);
            if (gm < M) aReg[i] = *(const float4*)&A[(size_t)gm * K + kk0 + k4 * 4];
            int bk = idx >> 5, n4 = idx & 31;
            bReg[i] = make_float4(0.f, 0.f, 0.f, 0.f);
            if (n0 + n4 * 4 < N) bReg[i] = *(const float4*)&B[(size_t)(kk0 + bk) * N + n0 + n4 * 4];
        }
    };

    prefetch(0);
    float acc[2][2][4][4] = {};  // [ri][ci][i][j]
    const int nk = K / BK;
    for (int t = 0; t < nk; ++t) {
        __syncthreads();  // previous compute done; LDS safe to overwrite
#pragma unroll
        for (int i = 0; i < 2; ++i) {
            int idx = tid + i * 256;
            int m = idx >> 2, k4 = idx & 3;
            As[k4 * 4 + 0][m] = aReg[i].x;
            As[k4 * 4 + 1][m] = aReg[i].y;
            As[k4 * 4 + 2][m] = aReg[i].z;
            As[k4 * 4 + 3][m] = aReg[i].w;
            int bk = idx >> 5, n4 = idx & 31;
            *(float4*)&Bs[bk][n4 * 4] = bReg[i];
        }
        __syncthreads();  // LDS visible
        if (t + 1 < nk) prefetch((t + 1) * BK);  // loads fly during compute
#pragma unroll
        for (int k = 0; k < BK; ++k) {
            float4 a0 = *(const float4*)&As[k][ty * 4];
            float4 a1 = *(const float4*)&As[k][64 + ty * 4];
            float4 b0 = *(const float4*)&Bs[k][tx * 4];
            float4 b1 = *(const float4*)&Bs[k][64 + tx * 4];
            float a[2][4] = {{a0.x, a0.y, a0.z, a0.w}, {a1.x, a1.y, a1.z, a1.w}};
            float b[2][4] = {{b0.x, b0.y, b0.z, b0.w}, {b1.x, b1.y, b1.z, b1.w}};
#pragma unroll
            for (int ri = 0; ri < 2; ++ri)
#pragma unroll
                for (int ci = 0; ci < 2; ++ci)
#pragma unroll
                    for (int i = 0; i < 4; ++i)
#pragma unroll
                        for (int j = 0; j < 4; ++j) acc[ri][ci][i][j] += a[ri][i] * b[ci][j];
        }
    }
    // attention vectors for this thread's 8 columns
    float asv[2][4], adv[2][4];
#pragma unroll
    for (int ci = 0; ci < 2; ++ci)
#pragma unroll
        for (int j = 0; j < 4; ++j) {
            int c = n0 + ci * 64 + tx * 4 + j;
            asv[ci][j] = (c < N) ? as_[c] : 0.f;
            adv[ci][j] = (c < N) ? ad_[c] : 0.f;
        }
    constexpr int W = F / 4;  // lanes per head segment (8 or 16)
#pragma unroll
    for (int ri = 0; ri < 2; ++ri)
#pragma unroll
        for (int i = 0; i < 4; ++i) {
            int gm = m0 + ri * 64 + ty * 4 + i;
            bool rowok = gm < M;
#pragma unroll
            for (int ci = 0; ci < 2; ++ci) {
                int c0 = n0 + ci * 64 + tx * 4;
                if (c0 < N) {  // uniform per ci (N % 64 == 0)
                    if (rowok) {
                        __hip_bfloat16 tmp[4];
#pragma unroll
                        for (int j = 0; j < 4; ++j) tmp[j] = __float2bfloat16(acc[ri][ci][i][j]);
                        *(uint2*)&C[(size_t)gm * N + c0] = *(uint2*)tmp;
                    }
                    float ps = 0.f, pd = 0.f;
#pragma unroll
                    for (int j = 0; j < 4; ++j) {
                        ps += acc[ri][ci][i][j] * asv[ci][j];
                        pd += acc[ri][ci][i][j] * adv[ci][j];
                    }
#pragma unroll
                    for (int off = W / 2; off > 0; off >>= 1) {
                        ps += __shfl_down(ps, off, W);
                        pd += __shfl_down(pd, off, W);
                    }
                    if (rowok && (tx & (W - 1)) == 0) {
                        int hd = c0 / F;
                        es[(size_t)gm * HHEADS + hd] = ps;
                        ed[(size_t)gm * HHEADS + hd] = pd;
                    }
                }
            }
        }
}

// ---------------- edge softmax: dst-centric, atomic-free ----------------
// Pass 1 gathers es (random), caches leaky-relu logits in alpha (sequential);
// pass 2 re-reads alpha sequentially -> exp -> rewrite, sum.
__global__ void edge_softmax(const float* __restrict__ es, const float* __restrict__ ed,
                             const int* __restrict__ offsets, const int* __restrict__ ssrc,
                             float* __restrict__ alpha, float* __restrict__ denom, int n) {
    int i = blockIdx.x * blockDim.x + threadIdx.x;
    if (i >= n * HHEADS) return;
    int node = i / HHEADS, hd = i % HHEADS;
    int a = offsets[node], b = offsets[node + 1];
    float edv = ed[i];
    float m = -1e30f;
    for (int j = a; j < b; ++j) {
        float v = es[ssrc[j] * HHEADS + hd] + edv;
        v = v > 0.f ? v : 0.2f * v;  // leaky relu 0.2
        alpha[(size_t)j * HHEADS + hd] = v;
        m = fmaxf(m, v);
    }
    float sum = 0.f;
    for (int j = a; j < b; ++j) {
        float ex = expf(alpha[(size_t)j * HHEADS + hd] - m);
        alpha[(size_t)j * HHEADS + hd] = ex;
        sum += ex;
    }
    denom[i] = sum;
}

// thread per (node, 8-channel group); 16B uint4 gathers of bf16 h[src].
template <int F>
__global__ void aggregate_kernel(const __hip_bfloat16* __restrict__ h,
                                 const float* __restrict__ alpha,
                                 const float* __restrict__ denom,
                                 const int* __restrict__ offsets, const int* __restrict__ ssrc,
                                 float* __restrict__ out, int n) {
    constexpr int HF = HHEADS * F;
    constexpr int C8 = HF / 8;
    int tid = blockIdx.x * blockDim.x + threadIdx.x;
    if (tid >= n * C8) return;
    int node = tid / C8, q = tid % C8;
    int c = q * 8, hd = c / F;
    int a = offsets[node], b = offsets[node + 1];
    float acc[8] = {};
    for (int j = a; j < b; ++j) {
        int s = ssrc[j];
        float al = alpha[(size_t)j * HHEADS + hd];
        uint4 hv = *(const uint4*)&h[(size_t)s * HF + c];
        acc[0] += al * bfl(hv.x);
        acc[1] += al * bfh(hv.x);
        acc[2] += al * bfl(hv.y);
        acc[3] += al * bfh(hv.y);
        acc[4] += al * bfl(hv.z);
        acc[5] += al * bfh(hv.z);
        acc[6] += al * bfl(hv.w);
        acc[7] += al * bfh(hv.w);
    }
    float invd = 1.0f / (denom[node * HHEADS + hd] + 1e-16f);
    float4 o0, o1;
    float* op = &o0.x;
#pragma unroll
    for (int k = 0; k < 8; ++k) {
        float v = acc[k] * invd;
        v = v > 0.f ? v : (expf(v) - 1.0f);  // elu
        op[k] = v;
    }
    *(float4*)&out[(size_t)node * HF + c] = o0;
    *(float4*)&out[(size_t)node * HF + c + 4] = o1;
}

// ---------------- pooling + head ----------------
__global__ void pool_kernel(const float* __restrict__ out3, float* __restrict__ g, int n) {
    int b = blockIdx.x, t = threadIdx.x;
    int chunk = (n + gridDim.x - 1) / gridDim.x;
    int n0 = b * chunk, n1 = min(n, n0 + chunk);
    float a0 = 0.f, a1 = 0.f;
    for (int node = n0; node < n1; ++node) {
        a0 += out3[(size_t)node * 384 + t];
        if (t < 128) a1 += out3[(size_t)node * 384 + 256 + t];
    }
    atomicAdd(&g[t], a0);
    if (t < 128) atomicAdd(&g[256 + t], a1);
}

__global__ void final_kernel(const float* __restrict__ g, const float* __restrict__ Wd,
                             const float* __restrict__ bd, float* __restrict__ outp) {
    __shared__ float red[384];
    int t = threadIdx.x;  // blockDim = 384
    float v = g[t];
    red[t] = v * v;
    __syncthreads();
    for (int s = 192; s >= 3; s >>= 1) {
        if (t < s) red[t] += red[t + s];
        __syncthreads();
    }
    __shared__ float scale_s;
    if (t == 0) {
        float norm = sqrtf(red[0] + red[1] + red[2]);
        scale_s = 1.0f / fmaxf(norm, 1e-12f);
    }
    __syncthreads();
    float scale = scale_s;
    red[t] = v * scale * Wd[t];
    __syncthreads();
    for (int s = 192; s >= 3; s >>= 1) {
        if (t < s) red[t] += red[t + s];
        __syncthreads();
    }
    if (t == 0) outp[0] = red[0] + red[1] + red[2] + bd[0];
}

// ---------------- host side ----------------
template <int F>
static void run_edges_and_agg(__hip_bfloat16* hbuf, float* outbuf, float* es, float* ed,
                              float* denom, float* alpha, const int* offsets, const int* ssrc,
                              int N, int E, hipStream_t stream) {
    constexpr int HF = HHEADS * F;
    edge_softmax<<<(N * HHEADS + 255) / 256, 256, 0, stream>>>(es, ed, offsets, ssrc, alpha,
                                                               denom, N);
    long total = (long)N * HF / 8;
    aggregate_kernel<F><<<(total + 255) / 256, 256, 0, stream>>>(hbuf, alpha, denom, offsets,
                                                                 ssrc, outbuf, N);
}

extern "C" void kernel_launch(void* const* d_in, const int* in_sizes, int n_in, void* d_out,
                              int out_size, void* d_ws, size_t ws_size, hipStream_t stream) {
    const float* x = (const float*)d_in[0];
    const int* ei = (const int*)d_in[1];
    const float* W1 = (const float*)d_in[2];
    const float* a1s = (const float*)d_in[3];
    const float* a1d = (const float*)d_in[4];
    const float* W2 = (const float*)d_in[5];
    const float* a2s = (const float*)d_in[6];
    const float* a2d = (const float*)d_in[7];
    const float* W3 = (const float*)d_in[8];
    const float* a3s = (const float*)d_in[9];
    const float* a3d = (const float*)d_in[10];
    const float* Wd = (const float*)d_in[11];
    const float* bd = (const float*)d_in[12];
    float* outp = (float*)d_out;

    const int N = in_sizes[0] / 11;
    const int E = in_sizes[1] / 2;
    const int* src = ei;
    const int* dst = ei + E;

    char* w = (char*)d_ws;
    size_t off = 0;
    auto A = [&](size_t bytes) {
        size_t o = off;
        off += (bytes + 255) & ~(size_t)255;
        return o;
    };
    __hip_bfloat16* bufH = (__hip_bfloat16*)(w + A((size_t)N * 384 * 2));  // bf16 h
    float* bufA = (float*)(w + A((size_t)N * 384 * 4));  // layer1 out (96), layer3 out (384)
    float* bufB = (float*)(w + A((size_t)N * 192 * 4));  // layer2 out
    float* es = (float*)(w + A((size_t)N * HHEADS * 4));
    float* ed = (float*)(w + A((size_t)N * HHEADS * 4));
    float* denom = (float*)(w + A((size_t)N * HHEADS * 4));
    float* alpha = (float*)(w + A((size_t)E * HHEADS * 4));
    float* wp = (float*)(w + A((size_t)192 * 384 * 4));  // repacked W, max layer3
    int* count = (int*)(w + A((size_t)(N + 1) * 4));
    int* cursor = (int*)(w + A((size_t)(N + 1) * 4));
    int* offsets = (int*)(w + A((size_t)(N + 1) * 4));
    int* bsum = (int*)(w + A(64 * 4));
    int* ssrc = (int*)(w + A((size_t)E * 4));
    float* g = (float*)(w + A(384 * 4));

    // CSR build (by dst)
    hipMemsetAsync(count, 0, (size_t)N * 4, stream);
    hipMemsetAsync(cursor, 0, (size_t)N * 4, stream);
    hist_kernel<<<(E + 255) / 256, 256, 0, stream>>>(dst, count, E);
    int nb = (N + 1023) / 1024;  // 49 <= 64
    scan_block<<<nb, 1024, 0, stream>>>(count, offsets, bsum, N);
    scan_tops<<<1, 64, 0, stream>>>(bsum, nb);
    scan_add<<<nb, 1024, 0, stream>>>(offsets, bsum, N, E);
    scatter_kernel<<<(E + 255) / 256, 256, 0, stream>>>(src, dst, offsets, cursor, ssrc, E);

    // ---- layer 1 (FIN=11, F=16) ----
    repack_w<<<(11 * 96 + 255) / 256, 256, 0, stream>>>(W1, wp, 11, 16);
    {
        dim3 grid((96 + 63) / 64, (N + 63) / 64);
        gemm_small<64, 64, 32><<<grid, 256, 0, stream>>>(x, wp, bufH, N, 11, 96);
    }
    attn_terms<16><<<N, 96, 0, stream>>>(bufH, a1s, a1d, es, ed);
    run_edges_and_agg<16>(bufH, bufA, es, ed, denom, alpha, offsets, ssrc, N, E, stream);

    // ---- layer 2 (FIN=96, F=32) ----
    repack_w<<<(96 * 192 + 255) / 256, 256, 0, stream>>>(W2, wp, 96, 32);
    {
        dim3 grid((192 + 127) / 128, (N + 127) / 128);
        gemm_attn<32><<<grid, 256, 0, stream>>>(bufA, wp, bufH, a2s, a2d, es, ed, N, 96, 192);
    }
    run_edges_and_agg<32>(bufH, bufB, es, ed, denom, alpha, offsets, ssrc, N, E, stream);

    // ---- layer 3 (FIN=192, F=64) ----
    repack_w<<<(192 * 384 + 255) / 256, 256, 0, stream>>>(W3, wp, 192, 64);
    {
        dim3 grid((384 + 127) / 128, (N + 127) / 128);
        gemm_attn<64><<<grid, 256, 0, stream>>>(bufB, wp, bufH, a3s, a3d, es, ed, N, 192, 384);
    }
    run_edges_and_agg<64>(bufH, bufA, es, ed, denom, alpha, offsets, ssrc, N, E, stream);

    // sum-pool -> normalize -> dense
    hipMemsetAsync(g, 0, 384 * 4, stream);
    pool_kernel<<<256, 256, 0, stream>>>(bufA, g, N);
    final_kernel<<<1, 384, 0, stream>>>(g, Wd, bd, outp);
}

// Round 8
// 640.413 us; speedup vs baseline: 1.8530x; 1.1398x over previous
//
#include <hip/hip_runtime.h>
#include <hip/hip_bf16.h>

// GAT 3-layer: N=50000 nodes, E=800000 edges, H=6 heads.
// CSR-by-dst built per call; dst-centric atomic-free aggregation.
// R1: transforms = tiled f32 GEMMs (W re-read was L2-BW bound at 577us).
// R2: dst-centric edge softmax over CSR (zero atomics), alpha in CSR order.
// R3: h stored bf16 (aggregate was fetch-BW bound); f32 accumulate everywhere.
// R4: layers 2/3 GEMM = 128x128 tile, 8x8 split micro-tile, fused attn epilogue.
// R5: gemm_attn register-double-buffer; parallel 3-phase CSR scan.
// R6: fix R5 spill (launch_bounds(256,4) forced VGPR 64 -> 1GB scratch traffic).
// R7: edge softmax FUSED into aggregate (online max/sum rescale, flash-style):
//     kills 3 dispatches + alpha logit/exp round-trips (~114 MB/layer traffic).

#define HHEADS 6

__device__ __forceinline__ float bfl(unsigned u) { return __uint_as_float(u << 16); }
__device__ __forceinline__ float bfh(unsigned u) { return __uint_as_float(u & 0xffff0000u); }

// ---------------- CSR build ----------------
__global__ void hist_kernel(const int* __restrict__ dst, int* __restrict__ count, int E) {
    int e = blockIdx.x * blockDim.x + threadIdx.x;
    if (e >= E) return;
    atomicAdd(&count[dst[e]], 1);
}

// phase A: per-1024-block exclusive scan + block totals
__global__ void scan_block(const int* __restrict__ count, int* __restrict__ offsets,
                           int* __restrict__ bsum, int n) {
    __shared__ int s[1024];
    int i = blockIdx.x * 1024 + threadIdx.x;
    int v = (i < n) ? count[i] : 0;
    s[threadIdx.x] = v;
    __syncthreads();
    for (int off = 1; off < 1024; off <<= 1) {
        int t = (threadIdx.x >= (unsigned)off) ? s[threadIdx.x - off] : 0;
        __syncthreads();
        s[threadIdx.x] += t;
        __syncthreads();
    }
    if (i < n) offsets[i] = s[threadIdx.x] - v;
    if (threadIdx.x == 1023) bsum[blockIdx.x] = s[1023];
}

// phase B: single block scans block totals (nb <= 64)
__global__ void scan_tops(int* __restrict__ bsum, int nb) {
    __shared__ int s[64];
    int t = threadIdx.x;  // blockDim = 64
    int v = (t < nb) ? bsum[t] : 0;
    s[t] = v;
    __syncthreads();
    for (int off = 1; off < 64; off <<= 1) {
        int tmp = (t >= off) ? s[t - off] : 0;
        __syncthreads();
        s[t] += tmp;
        __syncthreads();
    }
    if (t < nb) bsum[t] = s[t] - v;  // exclusive
}

// phase C: add block offsets; write sentinel
__global__ void scan_add(int* __restrict__ offsets, const int* __restrict__ bsum, int n,
                         int total) {
    int i = blockIdx.x * 1024 + threadIdx.x;
    if (i < n) offsets[i] += bsum[blockIdx.x];
    if (i == 0) offsets[n] = total;
}

__global__ void scatter_kernel(const int* __restrict__ src, const int* __restrict__ dst,
                               const int* __restrict__ offsets, int* __restrict__ cursor,
                               int* __restrict__ ssrc, int E) {
    int e = blockIdx.x * blockDim.x + threadIdx.x;
    if (e >= E) return;
    int d = dst[e];
    int pos = offsets[d] + atomicAdd(&cursor[d], 1);
    ssrc[pos] = src[e];
}

// ---------------- weight repack: Wp[k*HF + hd*F + f] = W[hd,k,f] ----------------
__global__ void repack_w(const float* __restrict__ W, float* __restrict__ Wp, int FIN, int F) {
    int HF = HHEADS * F;
    int i = blockIdx.x * blockDim.x + threadIdx.x;
    if (i >= FIN * HF) return;
    int k = i / HF, c = i % HF;
    int hd = c / F, f = c % F;
    Wp[i] = W[(hd * FIN + k) * F + f];
}

// ---------------- small GEMM (layer 1, K=11): 64x64, 4x4 micro-tile ----------------
template <int BM, int BN, int BK>
__global__ __launch_bounds__(256) void gemm_small(const float* __restrict__ A,
                                                  const float* __restrict__ B,
                                                  __hip_bfloat16* __restrict__ C, int M,
                                                  int K, int N) {
    __shared__ float As[BK][BM + 4];
    __shared__ float Bs[BK][BN];
    int tid = threadIdx.x;
    int tx = tid % 16, ty = tid / 16;
    int m0 = blockIdx.y * BM, n0 = blockIdx.x * BN;
    float acc[4][4] = {};
    for (int kk0 = 0; kk0 < K; kk0 += BK) {
#pragma unroll
        for (int i = 0; i < (BM * BK) / 256; ++i) {
            int idx = tid + i * 256;
            int m = idx / BK, k = idx % BK;
            float v = 0.f;
            if (m0 + m < M && kk0 + k < K) v = A[(size_t)(m0 + m) * K + kk0 + k];
            As[k][m] = v;
        }
#pragma unroll
        for (int i = 0; i < (BK * BN) / 1024; ++i) {
            int idx = tid + i * 256;
            int k = idx / (BN / 4), n4 = idx % (BN / 4);
            float4 v = make_float4(0.f, 0.f, 0.f, 0.f);
            if (kk0 + k < K && n0 + n4 * 4 < N)
                v = *(const float4*)&B[(size_t)(kk0 + k) * N + n0 + n4 * 4];
            *(float4*)&Bs[k][n4 * 4] = v;
        }
        __syncthreads();
#pragma unroll
        for (int k = 0; k < BK; ++k) {
            float4 av = *(const float4*)&As[k][ty * 4];
            float4 bv = *(const float4*)&Bs[k][tx * 4];
            float a[4] = {av.x, av.y, av.z, av.w};
            float b[4] = {bv.x, bv.y, bv.z, bv.w};
#pragma unroll
            for (int i = 0; i < 4; ++i)
#pragma unroll
                for (int j = 0; j < 4; ++j) acc[i][j] += a[i] * b[j];
        }
        __syncthreads();
    }
#pragma unroll
    for (int i = 0; i < 4; ++i) {
        int m = m0 + ty * 4 + i;
        if (m < M && n0 + tx * 4 < N) {
            __hip_bfloat16 tmp[4];
#pragma unroll
            for (int j = 0; j < 4; ++j) tmp[j] = __float2bfloat16(acc[i][j]);
            *(uint2*)&C[(size_t)m * N + n0 + tx * 4] = *(uint2*)tmp;
        }
    }
}

// es[n,hd] for layer 1; block = HF threads, one node per block.
template <int F>
__global__ void attn_terms(const __hip_bfloat16* __restrict__ h, const float* __restrict__ as_,
                           const float* __restrict__ ad_, float* __restrict__ es,
                           float* __restrict__ ed) {
    constexpr int HF = HHEADS * F;
    int node = blockIdx.x;
    int t = threadIdx.x;
    float v = __bfloat162float(h[(size_t)node * HF + t]);
    float s = v * as_[t];
    float d = v * ad_[t];
#pragma unroll
    for (int off = F / 2; off > 0; off >>= 1) {
        s += __shfl_down(s, off, F);
        d += __shfl_down(d, off, F);
    }
    if ((t & (F - 1)) == 0) {
        int hd = t / F;
        es[node * HHEADS + hd] = s;
        ed[node * HHEADS + hd] = d;
    }
}

// ---------------- big GEMM + fused attn (layers 2/3) ----------------
// C[M,N] = A[M,K] @ B[K,N], C bf16; es/ed from f32 acc in epilogue.
// BM=BN=128, BK=16, 256 threads, 8x8 micro-tile as 2x2 split 4x4 blocks.
// Register double-buffer: prefetch tile t+1 during compute of tile t.
// NOTE: no min-waves pin in launch_bounds — (256,4) forced 64 VGPR and
// spilled the 64-reg accumulator to scratch (R5 regression).
// Requires: K % 16 == 0, N % 64 == 0, F in {32,64}.
template <int F>
__global__ __launch_bounds__(256) void gemm_attn(const float* __restrict__ A,
                                                 const float* __restrict__ B,
                                                 __hip_bfloat16* __restrict__ C,
                                                 const float* __restrict__ as_,
                                                 const float* __restrict__ ad_,
                                                 float* __restrict__ es,
                                                 float* __restrict__ ed, int M, int K,
                                                 int N) {
    constexpr int BM = 128, BN = 128, BK = 16;
    __shared__ float As[BK][BM + 4];  // stride 132: staging writes 2-way (free)
    __shared__ float Bs[BK][BN];
    int tid = threadIdx.x;
    int tx = tid % 16, ty = tid / 16;
    int m0 = blockIdx.y * BM, n0 = blockIdx.x * BN;

    float4 aReg[2], bReg[2];
    auto prefetch = [&](int kk0) {
#pragma unroll
        for (int i = 0; i < 2; ++i) {
            int idx = tid + i * 256;
            int m = idx >> 2, k4 = idx & 3;
            int gm = m0 + m;
            aReg[i] = make_float4(0.f, 0.f, 0.f, 0.f);
            if (gm < M) aReg[i] = *(const float4*)&A[(size_t)gm * K + kk0 + k4 * 4];
            int bk = idx >> 5, n4 = idx & 31;
            bReg[i] = make_float4(0.f, 0.f, 0.f, 0.f);
            if (n0 + n4 * 4 < N) bReg[i] = *(const float4*)&B[(size_t)(kk0 + bk) * N + n0 + n4 * 4];
        }
    };

    prefetch(0);
    float acc[2][2][4][4] = {};  // [ri][ci][i][j]
    const int nk = K / BK;
    for (int t = 0; t < nk; ++t) {
        __syncthreads();  // previous compute done; LDS safe to overwrite
#pragma unroll
        for (int i = 0; i < 2; ++i) {
            int idx = tid + i * 256;
            int m = idx >> 2, k4 = idx & 3;
            As[k4 * 4 + 0][m] = aReg[i].x;
            As[k4 * 4 + 1][m] = aReg[i].y;
            As[k4 * 4 + 2][m] = aReg[i].z;
            As[k4 * 4 + 3][m] = aReg[i].w;
            int bk = idx >> 5, n4 = idx & 31;
            *(float4*)&Bs[bk][n4 * 4] = bReg[i];
        }
        __syncthreads();  // LDS visible
        if (t + 1 < nk) prefetch((t + 1) * BK);  // loads fly during compute
#pragma unroll
        for (int k = 0; k < BK; ++k) {
            float4 a0 = *(const float4*)&As[k][ty * 4];
            float4 a1 = *(const float4*)&As[k][64 + ty * 4];
            float4 b0 = *(const float4*)&Bs[k][tx * 4];
            float4 b1 = *(const float4*)&Bs[k][64 + tx * 4];
            float a[2][4] = {{a0.x, a0.y, a0.z, a0.w}, {a1.x, a1.y, a1.z, a1.w}};
            float b[2][4] = {{b0.x, b0.y, b0.z, b0.w}, {b1.x, b1.y, b1.z, b1.w}};
#pragma unroll
            for (int ri = 0; ri < 2; ++ri)
#pragma unroll
                for (int ci = 0; ci < 2; ++ci)
#pragma unroll
                    for (int i = 0; i < 4; ++i)
#pragma unroll
                        for (int j = 0; j < 4; ++j) acc[ri][ci][i][j] += a[ri][i] * b[ci][j];
        }
    }
    // attention vectors for this thread's 8 columns
    float asv[2][4], adv[2][4];
#pragma unroll
    for (int ci = 0; ci < 2; ++ci)
#pragma unroll
        for (int j = 0; j < 4; ++j) {
            int c = n0 + ci * 64 + tx * 4 + j;
            asv[ci][j] = (c < N) ? as_[c] : 0.f;
            adv[ci][j] = (c < N) ? ad_[c] : 0.f;
        }
    constexpr int W = F / 4;  // lanes per head segment (8 or 16)
#pragma unroll
    for (int ri = 0; ri < 2; ++ri)
#pragma unroll
        for (int i = 0; i < 4; ++i) {
            int gm = m0 + ri * 64 + ty * 4 + i;
            bool rowok = gm < M;
#pragma unroll
            for (int ci = 0; ci < 2; ++ci) {
                int c0 = n0 + ci * 64 + tx * 4;
                if (c0 < N) {  // uniform per ci (N % 64 == 0)
                    if (rowok) {
                        __hip_bfloat16 tmp[4];
#pragma unroll
                        for (int j = 0; j < 4; ++j) tmp[j] = __float2bfloat16(acc[ri][ci][i][j]);
                        *(uint2*)&C[(size_t)gm * N + c0] = *(uint2*)tmp;
                    }
                    float ps = 0.f, pd = 0.f;
#pragma unroll
                    for (int j = 0; j < 4; ++j) {
                        ps += acc[ri][ci][i][j] * asv[ci][j];
                        pd += acc[ri][ci][i][j] * adv[ci][j];
                    }
#pragma unroll
                    for (int off = W / 2; off > 0; off >>= 1) {
                        ps += __shfl_down(ps, off, W);
                        pd += __shfl_down(pd, off, W);
                    }
                    if (rowok && (tx & (W - 1)) == 0) {
                        int hd = c0 / F;
                        es[(size_t)gm * HHEADS + hd] = ps;
                        ed[(size_t)gm * HHEADS + hd] = pd;
                    }
                }
            }
        }
}

// ---------------- fused edge softmax + aggregate (flash-style) ----------------
// thread per (node, 8-channel group). Online max/sum rescale over the CSR row:
// acc = acc*r + w*h[src], l = l*r + w, with r = exp(m_old - m_new), w = exp(v - m_new).
// es gathers hit the 1.2 MB L2-resident array; h gathers are the 16B uint4 bf16 loads.
template <int F>
__global__ void aggregate_fused(const __hip_bfloat16* __restrict__ h,
                                const float* __restrict__ es, const float* __restrict__ ed,
                                const int* __restrict__ offsets, const int* __restrict__ ssrc,
                                float* __restrict__ out, int n) {
    constexpr int HF = HHEADS * F;
    constexpr int C8 = HF / 8;
    int tid = blockIdx.x * blockDim.x + threadIdx.x;
    if (tid >= n * C8) return;
    int node = tid / C8, q = tid % C8;
    int c = q * 8, hd = c / F;
    int a = offsets[node], b = offsets[node + 1];
    float edv = ed[node * HHEADS + hd];
    float m = -1e30f, l = 0.f;
    float acc[8] = {};
    for (int j = a; j < b; ++j) {
        int s = ssrc[j];
        float v = es[s * HHEADS + hd] + edv;
        v = v > 0.f ? v : 0.2f * v;  // leaky relu 0.2
        float mn = fmaxf(m, v);
        float r = expf(m - mn);  // 1.0 when max unchanged, 0 on first edge
        float w = expf(v - mn);
        uint4 hv = *(const uint4*)&h[(size_t)s * HF + c];
        l = l * r + w;
        acc[0] = acc[0] * r + w * bfl(hv.x);
        acc[1] = acc[1] * r + w * bfh(hv.x);
        acc[2] = acc[2] * r + w * bfl(hv.y);
        acc[3] = acc[3] * r + w * bfh(hv.y);
        acc[4] = acc[4] * r + w * bfl(hv.z);
        acc[5] = acc[5] * r + w * bfh(hv.z);
        acc[6] = acc[6] * r + w * bfl(hv.w);
        acc[7] = acc[7] * r + w * bfh(hv.w);
        m = mn;
    }
    float invd = 1.0f / (l + 1e-16f);
    float4 o0, o1;
    float* op = &o0.x;
#pragma unroll
    for (int k = 0; k < 8; ++k) {
        float v = acc[k] * invd;
        v = v > 0.f ? v : (expf(v) - 1.0f);  // elu
        op[k] = v;
    }
    *(float4*)&out[(size_t)node * HF + c] = o0;
    *(float4*)&out[(size_t)node * HF + c + 4] = o1;
}

// ---------------- pooling + head ----------------
__global__ void pool_kernel(const float* __restrict__ out3, float* __restrict__ g, int n) {
    int b = blockIdx.x, t = threadIdx.x;
    int chunk = (n + gridDim.x - 1) / gridDim.x;
    int n0 = b * chunk, n1 = min(n, n0 + chunk);
    float a0 = 0.f, a1 = 0.f;
    for (int node = n0; node < n1; ++node) {
        a0 += out3[(size_t)node * 384 + t];
        if (t < 128) a1 += out3[(size_t)node * 384 + 256 + t];
    }
    atomicAdd(&g[t], a0);
    if (t < 128) atomicAdd(&g[256 + t], a1);
}

__global__ void final_kernel(const float* __restrict__ g, const float* __restrict__ Wd,
                             const float* __restrict__ bd, float* __restrict__ outp) {
    __shared__ float red[384];
    int t = threadIdx.x;  // blockDim = 384
    float v = g[t];
    red[t] = v * v;
    __syncthreads();
    for (int s = 192; s >= 3; s >>= 1) {
        if (t < s) red[t] += red[t + s];
        __syncthreads();
    }
    __shared__ float scale_s;
    if (t == 0) {
        float norm = sqrtf(red[0] + red[1] + red[2]);
        scale_s = 1.0f / fmaxf(norm, 1e-12f);
    }
    __syncthreads();
    float scale = scale_s;
    red[t] = v * scale * Wd[t];
    __syncthreads();
    for (int s = 192; s >= 3; s >>= 1) {
        if (t < s) red[t] += red[t + s];
        __syncthreads();
    }
    if (t == 0) outp[0] = red[0] + red[1] + red[2] + bd[0];
}

// ---------------- host side ----------------
extern "C" void kernel_launch(void* const* d_in, const int* in_sizes, int n_in, void* d_out,
                              int out_size, void* d_ws, size_t ws_size, hipStream_t stream) {
    const float* x = (const float*)d_in[0];
    const int* ei = (const int*)d_in[1];
    const float* W1 = (const float*)d_in[2];
    const float* a1s = (const float*)d_in[3];
    const float* a1d = (const float*)d_in[4];
    const float* W2 = (const float*)d_in[5];
    const float* a2s = (const float*)d_in[6];
    const float* a2d = (const float*)d_in[7];
    const float* W3 = (const float*)d_in[8];
    const float* a3s = (const float*)d_in[9];
    const float* a3d = (const float*)d_in[10];
    const float* Wd = (const float*)d_in[11];
    const float* bd = (const float*)d_in[12];
    float* outp = (float*)d_out;

    const int N = in_sizes[0] / 11;
    const int E = in_sizes[1] / 2;
    const int* src = ei;
    const int* dst = ei + E;

    char* w = (char*)d_ws;
    size_t off = 0;
    auto A = [&](size_t bytes) {
        size_t o = off;
        off += (bytes + 255) & ~(size_t)255;
        return o;
    };
    __hip_bfloat16* bufH = (__hip_bfloat16*)(w + A((size_t)N * 384 * 2));  // bf16 h
    float* bufA = (float*)(w + A((size_t)N * 384 * 4));  // layer1 out (96), layer3 out (384)
    float* bufB = (float*)(w + A((size_t)N * 192 * 4));  // layer2 out
    float* es = (float*)(w + A((size_t)N * HHEADS * 4));
    float* ed = (float*)(w + A((size_t)N * HHEADS * 4));
    float* wp = (float*)(w + A((size_t)192 * 384 * 4));  // repacked W, max layer3
    int* count = (int*)(w + A((size_t)(N + 1) * 4));
    int* cursor = (int*)(w + A((size_t)(N + 1) * 4));
    int* offsets = (int*)(w + A((size_t)(N + 1) * 4));
    int* bsum = (int*)(w + A(64 * 4));
    int* ssrc = (int*)(w + A((size_t)E * 4));
    float* g = (float*)(w + A(384 * 4));

    // CSR build (by dst)
    hipMemsetAsync(count, 0, (size_t)N * 4, stream);
    hipMemsetAsync(cursor, 0, (size_t)N * 4, stream);
    hist_kernel<<<(E + 255) / 256, 256, 0, stream>>>(dst, count, E);
    int nb = (N + 1023) / 1024;  // 49 <= 64
    scan_block<<<nb, 1024, 0, stream>>>(count, offsets, bsum, N);
    scan_tops<<<1, 64, 0, stream>>>(bsum, nb);
    scan_add<<<nb, 1024, 0, stream>>>(offsets, bsum, N, E);
    scatter_kernel<<<(E + 255) / 256, 256, 0, stream>>>(src, dst, offsets, cursor, ssrc, E);

    // ---- layer 1 (FIN=11, F=16) ----
    repack_w<<<(11 * 96 + 255) / 256, 256, 0, stream>>>(W1, wp, 11, 16);
    {
        dim3 grid((96 + 63) / 64, (N + 63) / 64);
        gemm_small<64, 64, 32><<<grid, 256, 0, stream>>>(x, wp, bufH, N, 11, 96);
    }
    attn_terms<16><<<N, 96, 0, stream>>>(bufH, a1s, a1d, es, ed);
    {
        long total = (long)N * 96 / 8;
        aggregate_fused<16><<<(total + 255) / 256, 256, 0, stream>>>(bufH, es, ed, offsets,
                                                                     ssrc, bufA, N);
    }

    // ---- layer 2 (FIN=96, F=32) ----
    repack_w<<<(96 * 192 + 255) / 256, 256, 0, stream>>>(W2, wp, 96, 32);
    {
        dim3 grid((192 + 127) / 128, (N + 127) / 128);
        gemm_attn<32><<<grid, 256, 0, stream>>>(bufA, wp, bufH, a2s, a2d, es, ed, N, 96, 192);
    }
    {
        long total = (long)N * 192 / 8;
        aggregate_fused<32><<<(total + 255) / 256, 256, 0, stream>>>(bufH, es, ed, offsets,
                                                                     ssrc, bufB, N);
    }

    // ---- layer 3 (FIN=192, F=64) ----
    repack_w<<<(192 * 384 + 255) / 256, 256, 0, stream>>>(W3, wp, 192, 64);
    {
        dim3 grid((384 + 127) / 128, (N + 127) / 128);
        gemm_attn<64><<<grid, 256, 0, stream>>>(bufB, wp, bufH, a3s, a3d, es, ed, N, 192, 384);
    }
    {
        long total = (long)N * 384 / 8;
        aggregate_fused<64><<<(total + 255) / 256, 256, 0, stream>>>(bufH, es, ed, offsets,
                                                                     ssrc, bufA, N);
    }

    // sum-pool -> normalize -> dense
    hipMemsetAsync(g, 0, 384 * 4, stream);
    pool_kernel<<<256, 256, 0, stream>>>(bufA, g, N);
    final_kernel<<<1, 384, 0, stream>>>(g, Wd, bd, outp);
}

// Round 9
// 639.420 us; speedup vs baseline: 1.8559x; 1.0016x over previous
//
#include <hip/hip_runtime.h>
#include <hip/hip_bf16.h>

// GAT 3-layer: N=50000 nodes, E=800000 edges, H=6 heads.
// CSR-by-dst built per call; dst-centric atomic-free aggregation.
// R1: transforms = tiled f32 GEMMs (W re-read was L2-BW bound at 577us).
// R2: dst-centric edge softmax over CSR (zero atomics), alpha in CSR order.
// R3: h stored bf16 (aggregate was fetch-BW bound); f32 accumulate everywhere.
// R4: layers 2/3 GEMM = 128x128 tile, 8x8 split micro-tile, fused attn epilogue.
// R5: gemm_attn register prefetch; parallel 3-phase CSR scan.
// R6: fix R5 spill (launch_bounds(256,4) forced VGPR 64 -> 1GB scratch traffic).
// R7: edge softmax fused into aggregate (flash-style online max/sum).
// R8: gemm_attn LDS double-buffer, ONE barrier per K-tile (was 2: VALUBusy
//     stuck at 52%, pure-VALU floor 47us vs 120us measured = barrier stall).

#define HHEADS 6

__device__ __forceinline__ float bfl(unsigned u) { return __uint_as_float(u << 16); }
__device__ __forceinline__ float bfh(unsigned u) { return __uint_as_float(u & 0xffff0000u); }

// ---------------- CSR build ----------------
__global__ void hist_kernel(const int* __restrict__ dst, int* __restrict__ count, int E) {
    int e = blockIdx.x * blockDim.x + threadIdx.x;
    if (e >= E) return;
    atomicAdd(&count[dst[e]], 1);
}

// phase A: per-1024-block exclusive scan + block totals
__global__ void scan_block(const int* __restrict__ count, int* __restrict__ offsets,
                           int* __restrict__ bsum, int n) {
    __shared__ int s[1024];
    int i = blockIdx.x * 1024 + threadIdx.x;
    int v = (i < n) ? count[i] : 0;
    s[threadIdx.x] = v;
    __syncthreads();
    for (int off = 1; off < 1024; off <<= 1) {
        int t = (threadIdx.x >= (unsigned)off) ? s[threadIdx.x - off] : 0;
        __syncthreads();
        s[threadIdx.x] += t;
        __syncthreads();
    }
    if (i < n) offsets[i] = s[threadIdx.x] - v;
    if (threadIdx.x == 1023) bsum[blockIdx.x] = s[1023];
}

// phase B: single block scans block totals (nb <= 64)
__global__ void scan_tops(int* __restrict__ bsum, int nb) {
    __shared__ int s[64];
    int t = threadIdx.x;  // blockDim = 64
    int v = (t < nb) ? bsum[t] : 0;
    s[t] = v;
    __syncthreads();
    for (int off = 1; off < 64; off <<= 1) {
        int tmp = (t >= off) ? s[t - off] : 0;
        __syncthreads();
        s[t] += tmp;
        __syncthreads();
    }
    if (t < nb) bsum[t] = s[t] - v;  // exclusive
}

// phase C: add block offsets; write sentinel
__global__ void scan_add(int* __restrict__ offsets, const int* __restrict__ bsum, int n,
                         int total) {
    int i = blockIdx.x * 1024 + threadIdx.x;
    if (i < n) offsets[i] += bsum[blockIdx.x];
    if (i == 0) offsets[n] = total;
}

__global__ void scatter_kernel(const int* __restrict__ src, const int* __restrict__ dst,
                               const int* __restrict__ offsets, int* __restrict__ cursor,
                               int* __restrict__ ssrc, int E) {
    int e = blockIdx.x * blockDim.x + threadIdx.x;
    if (e >= E) return;
    int d = dst[e];
    int pos = offsets[d] + atomicAdd(&cursor[d], 1);
    ssrc[pos] = src[e];
}

// ---------------- weight repack: Wp[k*HF + hd*F + f] = W[hd,k,f] ----------------
__global__ void repack_w(const float* __restrict__ W, float* __restrict__ Wp, int FIN, int F) {
    int HF = HHEADS * F;
    int i = blockIdx.x * blockDim.x + threadIdx.x;
    if (i >= FIN * HF) return;
    int k = i / HF, c = i % HF;
    int hd = c / F, f = c % F;
    Wp[i] = W[(hd * FIN + k) * F + f];
}

// ---------------- small GEMM (layer 1, K=11): 64x64, 4x4 micro-tile ----------------
template <int BM, int BN, int BK>
__global__ __launch_bounds__(256) void gemm_small(const float* __restrict__ A,
                                                  const float* __restrict__ B,
                                                  __hip_bfloat16* __restrict__ C, int M,
                                                  int K, int N) {
    __shared__ float As[BK][BM + 4];
    __shared__ float Bs[BK][BN];
    int tid = threadIdx.x;
    int tx = tid % 16, ty = tid / 16;
    int m0 = blockIdx.y * BM, n0 = blockIdx.x * BN;
    float acc[4][4] = {};
    for (int kk0 = 0; kk0 < K; kk0 += BK) {
#pragma unroll
        for (int i = 0; i < (BM * BK) / 256; ++i) {
            int idx = tid + i * 256;
            int m = idx / BK, k = idx % BK;
            float v = 0.f;
            if (m0 + m < M && kk0 + k < K) v = A[(size_t)(m0 + m) * K + kk0 + k];
            As[k][m] = v;
        }
#pragma unroll
        for (int i = 0; i < (BK * BN) / 1024; ++i) {
            int idx = tid + i * 256;
            int k = idx / (BN / 4), n4 = idx % (BN / 4);
            float4 v = make_float4(0.f, 0.f, 0.f, 0.f);
            if (kk0 + k < K && n0 + n4 * 4 < N)
                v = *(const float4*)&B[(size_t)(kk0 + k) * N + n0 + n4 * 4];
            *(float4*)&Bs[k][n4 * 4] = v;
        }
        __syncthreads();
#pragma unroll
        for (int k = 0; k < BK; ++k) {
            float4 av = *(const float4*)&As[k][ty * 4];
            float4 bv = *(const float4*)&Bs[k][tx * 4];
            float a[4] = {av.x, av.y, av.z, av.w};
            float b[4] = {bv.x, bv.y, bv.z, bv.w};
#pragma unroll
            for (int i = 0; i < 4; ++i)
#pragma unroll
                for (int j = 0; j < 4; ++j) acc[i][j] += a[i] * b[j];
        }
        __syncthreads();
    }
#pragma unroll
    for (int i = 0; i < 4; ++i) {
        int m = m0 + ty * 4 + i;
        if (m < M && n0 + tx * 4 < N) {
            __hip_bfloat16 tmp[4];
#pragma unroll
            for (int j = 0; j < 4; ++j) tmp[j] = __float2bfloat16(acc[i][j]);
            *(uint2*)&C[(size_t)m * N + n0 + tx * 4] = *(uint2*)tmp;
        }
    }
}

// es[n,hd] for layer 1; block = HF threads, one node per block.
template <int F>
__global__ void attn_terms(const __hip_bfloat16* __restrict__ h, const float* __restrict__ as_,
                           const float* __restrict__ ad_, float* __restrict__ es,
                           float* __restrict__ ed) {
    constexpr int HF = HHEADS * F;
    int node = blockIdx.x;
    int t = threadIdx.x;
    float v = __bfloat162float(h[(size_t)node * HF + t]);
    float s = v * as_[t];
    float d = v * ad_[t];
#pragma unroll
    for (int off = F / 2; off > 0; off >>= 1) {
        s += __shfl_down(s, off, F);
        d += __shfl_down(d, off, F);
    }
    if ((t & (F - 1)) == 0) {
        int hd = t / F;
        es[node * HHEADS + hd] = s;
        ed[node * HHEADS + hd] = d;
    }
}

// ---------------- big GEMM + fused attn (layers 2/3) ----------------
// C[M,N] = A[M,K] @ B[K,N], C bf16; es/ed from f32 acc in epilogue.
// BM=BN=128, BK=16, 256 threads, 8x8 micro-tile as 2x2 split 4x4 blocks.
// LDS DOUBLE-buffer + register prefetch: one __syncthreads per K-tile.
// Schedule at iter t: publish tile t+1 -> LDS[1^buf], prefetch tile t+2 -> regs,
// compute LDS[buf], barrier. Hazards fenced by the single barrier per iter.
// NOTE: no min-waves pin (launch_bounds(256,4) caused a VGPR-64 spill in R5).
// Requires: K % 16 == 0, N % 64 == 0, F in {32,64}.
template <int F>
__global__ __launch_bounds__(256) void gemm_attn(const float* __restrict__ A,
                                                 const float* __restrict__ B,
                                                 __hip_bfloat16* __restrict__ C,
                                                 const float* __restrict__ as_,
                                                 const float* __restrict__ ad_,
                                                 float* __restrict__ es,
                                                 float* __restrict__ ed, int M, int K,
                                                 int N) {
    constexpr int BM = 128, BN = 128, BK = 16;
    __shared__ float As[2][BK][BM + 4];  // stride 132: staging writes 2-way (free)
    __shared__ float Bs[2][BK][BN];
    int tid = threadIdx.x;
    int tx = tid % 16, ty = tid / 16;
    int m0 = blockIdx.y * BM, n0 = blockIdx.x * BN;

    float4 aReg[2], bReg[2];
    auto prefetch = [&](int kk0) {
#pragma unroll
        for (int i = 0; i < 2; ++i) {
            int idx = tid + i * 256;
            int m = idx >> 2, k4 = idx & 3;
            int gm = m0 + m;
            aReg[i] = make_float4(0.f, 0.f, 0.f, 0.f);
            if (gm < M) aReg[i] = *(const float4*)&A[(size_t)gm * K + kk0 + k4 * 4];
            int bk = idx >> 5, n4 = idx & 31;
            bReg[i] = make_float4(0.f, 0.f, 0.f, 0.f);
            if (n0 + n4 * 4 < N) bReg[i] = *(const float4*)&B[(size_t)(kk0 + bk) * N + n0 + n4 * 4];
        }
    };
    auto publish = [&](int buf) {
#pragma unroll
        for (int i = 0; i < 2; ++i) {
            int idx = tid + i * 256;
            int m = idx >> 2, k4 = idx & 3;
            As[buf][k4 * 4 + 0][m] = aReg[i].x;
            As[buf][k4 * 4 + 1][m] = aReg[i].y;
            As[buf][k4 * 4 + 2][m] = aReg[i].z;
            As[buf][k4 * 4 + 3][m] = aReg[i].w;
            int bk = idx >> 5, n4 = idx & 31;
            *(float4*)&Bs[buf][bk][n4 * 4] = bReg[i];
        }
    };

    const int nk = K / BK;
    prefetch(0);
    publish(0);
    if (nk > 1) prefetch(BK);
    __syncthreads();

    float acc[2][2][4][4] = {};  // [ri][ci][i][j]
    for (int t = 0; t < nk; ++t) {
        int buf = t & 1;
        if (t + 1 < nk) {
            publish(1 ^ buf);                         // regs hold tile t+1
            if (t + 2 < nk) prefetch((t + 2) * BK);   // loads fly during compute
        }
#pragma unroll
        for (int k = 0; k < BK; ++k) {
            float4 a0 = *(const float4*)&As[buf][k][ty * 4];
            float4 a1 = *(const float4*)&As[buf][k][64 + ty * 4];
            float4 b0 = *(const float4*)&Bs[buf][k][tx * 4];
            float4 b1 = *(const float4*)&Bs[buf][k][64 + tx * 4];
            float a[2][4] = {{a0.x, a0.y, a0.z, a0.w}, {a1.x, a1.y, a1.z, a1.w}};
            float b[2][4] = {{b0.x, b0.y, b0.z, b0.w}, {b1.x, b1.y, b1.z, b1.w}};
#pragma unroll
            for (int ri = 0; ri < 2; ++ri)
#pragma unroll
                for (int ci = 0; ci < 2; ++ci)
#pragma unroll
                    for (int i = 0; i < 4; ++i)
#pragma unroll
                        for (int j = 0; j < 4; ++j) acc[ri][ci][i][j] += a[ri][i] * b[ci][j];
        }
        __syncthreads();
    }
    // attention vectors for this thread's 8 columns
    float asv[2][4], adv[2][4];
#pragma unroll
    for (int ci = 0; ci < 2; ++ci)
#pragma unroll
        for (int j = 0; j < 4; ++j) {
            int c = n0 + ci * 64 + tx * 4 + j;
            asv[ci][j] = (c < N) ? as_[c] : 0.f;
            adv[ci][j] = (c < N) ? ad_[c] : 0.f;
        }
    constexpr int W = F / 4;  // lanes per head segment (8 or 16)
#pragma unroll
    for (int ri = 0; ri < 2; ++ri)
#pragma unroll
        for (int i = 0; i < 4; ++i) {
            int gm = m0 + ri * 64 + ty * 4 + i;
            bool rowok = gm < M;
#pragma unroll
            for (int ci = 0; ci < 2; ++ci) {
                int c0 = n0 + ci * 64 + tx * 4;
                if (c0 < N) {  // uniform per ci (N % 64 == 0)
                    if (rowok) {
                        __hip_bfloat16 tmp[4];
#pragma unroll
                        for (int j = 0; j < 4; ++j) tmp[j] = __float2bfloat16(acc[ri][ci][i][j]);
                        *(uint2*)&C[(size_t)gm * N + c0] = *(uint2*)tmp;
                    }
                    float ps = 0.f, pd = 0.f;
#pragma unroll
                    for (int j = 0; j < 4; ++j) {
                        ps += acc[ri][ci][i][j] * asv[ci][j];
                        pd += acc[ri][ci][i][j] * adv[ci][j];
                    }
#pragma unroll
                    for (int off = W / 2; off > 0; off >>= 1) {
                        ps += __shfl_down(ps, off, W);
                        pd += __shfl_down(pd, off, W);
                    }
                    if (rowok && (tx & (W - 1)) == 0) {
                        int hd = c0 / F;
                        es[(size_t)gm * HHEADS + hd] = ps;
                        ed[(size_t)gm * HHEADS + hd] = pd;
                    }
                }
            }
        }
}

// ---------------- fused edge softmax + aggregate (flash-style) ----------------
template <int F>
__global__ void aggregate_fused(const __hip_bfloat16* __restrict__ h,
                                const float* __restrict__ es, const float* __restrict__ ed,
                                const int* __restrict__ offsets, const int* __restrict__ ssrc,
                                float* __restrict__ out, int n) {
    constexpr int HF = HHEADS * F;
    constexpr int C8 = HF / 8;
    int tid = blockIdx.x * blockDim.x + threadIdx.x;
    if (tid >= n * C8) return;
    int node = tid / C8, q = tid % C8;
    int c = q * 8, hd = c / F;
    int a = offsets[node], b = offsets[node + 1];
    float edv = ed[node * HHEADS + hd];
    float m = -1e30f, l = 0.f;
    float acc[8] = {};
    for (int j = a; j < b; ++j) {
        int s = ssrc[j];
        float v = es[s * HHEADS + hd] + edv;
        v = v > 0.f ? v : 0.2f * v;  // leaky relu 0.2
        float mn = fmaxf(m, v);
        float r = expf(m - mn);
        float w = expf(v - mn);
        uint4 hv = *(const uint4*)&h[(size_t)s * HF + c];
        l = l * r + w;
        acc[0] = acc[0] * r + w * bfl(hv.x);
        acc[1] = acc[1] * r + w * bfh(hv.x);
        acc[2] = acc[2] * r + w * bfl(hv.y);
        acc[3] = acc[3] * r + w * bfh(hv.y);
        acc[4] = acc[4] * r + w * bfl(hv.z);
        acc[5] = acc[5] * r + w * bfh(hv.z);
        acc[6] = acc[6] * r + w * bfl(hv.w);
        acc[7] = acc[7] * r + w * bfh(hv.w);
        m = mn;
    }
    float invd = 1.0f / (l + 1e-16f);
    float4 o0, o1;
    float* op = &o0.x;
#pragma unroll
    for (int k = 0; k < 8; ++k) {
        float v = acc[k] * invd;
        v = v > 0.f ? v : (expf(v) - 1.0f);  // elu
        op[k] = v;
    }
    *(float4*)&out[(size_t)node * HF + c] = o0;
    *(float4*)&out[(size_t)node * HF + c + 4] = o1;
}

// ---------------- pooling + head ----------------
__global__ void pool_kernel(const float* __restrict__ out3, float* __restrict__ g, int n) {
    int b = blockIdx.x, t = threadIdx.x;
    int chunk = (n + gridDim.x - 1) / gridDim.x;
    int n0 = b * chunk, n1 = min(n, n0 + chunk);
    float a0 = 0.f, a1 = 0.f;
    for (int node = n0; node < n1; ++node) {
        a0 += out3[(size_t)node * 384 + t];
        if (t < 128) a1 += out3[(size_t)node * 384 + 256 + t];
    }
    atomicAdd(&g[t], a0);
    if (t < 128) atomicAdd(&g[256 + t], a1);
}

__global__ void final_kernel(const float* __restrict__ g, const float* __restrict__ Wd,
                             const float* __restrict__ bd, float* __restrict__ outp) {
    __shared__ float red[384];
    int t = threadIdx.x;  // blockDim = 384
    float v = g[t];
    red[t] = v * v;
    __syncthreads();
    for (int s = 192; s >= 3; s >>= 1) {
        if (t < s) red[t] += red[t + s];
        __syncthreads();
    }
    __shared__ float scale_s;
    if (t == 0) {
        float norm = sqrtf(red[0] + red[1] + red[2]);
        scale_s = 1.0f / fmaxf(norm, 1e-12f);
    }
    __syncthreads();
    float scale = scale_s;
    red[t] = v * scale * Wd[t];
    __syncthreads();
    for (int s = 192; s >= 3; s >>= 1) {
        if (t < s) red[t] += red[t + s];
        __syncthreads();
    }
    if (t == 0) outp[0] = red[0] + red[1] + red[2] + bd[0];
}

// ---------------- host side ----------------
extern "C" void kernel_launch(void* const* d_in, const int* in_sizes, int n_in, void* d_out,
                              int out_size, void* d_ws, size_t ws_size, hipStream_t stream) {
    const float* x = (const float*)d_in[0];
    const int* ei = (const int*)d_in[1];
    const float* W1 = (const float*)d_in[2];
    const float* a1s = (const float*)d_in[3];
    const float* a1d = (const float*)d_in[4];
    const float* W2 = (const float*)d_in[5];
    const float* a2s = (const float*)d_in[6];
    const float* a2d = (const float*)d_in[7];
    const float* W3 = (const float*)d_in[8];
    const float* a3s = (const float*)d_in[9];
    const float* a3d = (const float*)d_in[10];
    const float* Wd = (const float*)d_in[11];
    const float* bd = (const float*)d_in[12];
    float* outp = (float*)d_out;

    const int N = in_sizes[0] / 11;
    const int E = in_sizes[1] / 2;
    const int* src = ei;
    const int* dst = ei + E;

    char* w = (char*)d_ws;
    size_t off = 0;
    auto A = [&](size_t bytes) {
        size_t o = off;
        off += (bytes + 255) & ~(size_t)255;
        return o;
    };
    __hip_bfloat16* bufH = (__hip_bfloat16*)(w + A((size_t)N * 384 * 2));  // bf16 h
    float* bufA = (float*)(w + A((size_t)N * 384 * 4));  // layer1 out (96), layer3 out (384)
    float* bufB = (float*)(w + A((size_t)N * 192 * 4));  // layer2 out
    float* es = (float*)(w + A((size_t)N * HHEADS * 4));
    float* ed = (float*)(w + A((size_t)N * HHEADS * 4));
    float* wp = (float*)(w + A((size_t)192 * 384 * 4));  // repacked W, max layer3
    int* count = (int*)(w + A((size_t)(N + 1) * 4));
    int* cursor = (int*)(w + A((size_t)(N + 1) * 4));
    int* offsets = (int*)(w + A((size_t)(N + 1) * 4));
    int* bsum = (int*)(w + A(64 * 4));
    int* ssrc = (int*)(w + A((size_t)E * 4));
    float* g = (float*)(w + A(384 * 4));

    // CSR build (by dst)
    hipMemsetAsync(count, 0, (size_t)N * 4, stream);
    hipMemsetAsync(cursor, 0, (size_t)N * 4, stream);
    hist_kernel<<<(E + 255) / 256, 256, 0, stream>>>(dst, count, E);
    int nb = (N + 1023) / 1024;  // 49 <= 64
    scan_block<<<nb, 1024, 0, stream>>>(count, offsets, bsum, N);
    scan_tops<<<1, 64, 0, stream>>>(bsum, nb);
    scan_add<<<nb, 1024, 0, stream>>>(offsets, bsum, N, E);
    scatter_kernel<<<(E + 255) / 256, 256, 0, stream>>>(src, dst, offsets, cursor, ssrc, E);

    // ---- layer 1 (FIN=11, F=16) ----
    repack_w<<<(11 * 96 + 255) / 256, 256, 0, stream>>>(W1, wp, 11, 16);
    {
        dim3 grid((96 + 63) / 64, (N + 63) / 64);
        gemm_small<64, 64, 32><<<grid, 256, 0, stream>>>(x, wp, bufH, N, 11, 96);
    }
    attn_terms<16><<<N, 96, 0, stream>>>(bufH, a1s, a1d, es, ed);
    {
        long total = (long)N * 96 / 8;
        aggregate_fused<16><<<(total + 255) / 256, 256, 0, stream>>>(bufH, es, ed, offsets,
                                                                     ssrc, bufA, N);
    }

    // ---- layer 2 (FIN=96, F=32) ----
    repack_w<<<(96 * 192 + 255) / 256, 256, 0, stream>>>(W2, wp, 96, 32);
    {
        dim3 grid((192 + 127) / 128, (N + 127) / 128);
        gemm_attn<32><<<grid, 256, 0, stream>>>(bufA, wp, bufH, a2s, a2d, es, ed, N, 96, 192);
    }
    {
        long total = (long)N * 192 / 8;
        aggregate_fused<32><<<(total + 255) / 256, 256, 0, stream>>>(bufH, es, ed, offsets,
                                                                     ssrc, bufB, N);
    }

    // ---- layer 3 (FIN=192, F=64) ----
    repack_w<<<(192 * 384 + 255) / 256, 256, 0, stream>>>(W3, wp, 192, 64);
    {
        dim3 grid((384 + 127) / 128, (N + 127) / 128);
        gemm_attn<64><<<grid, 256, 0, stream>>>(bufB, wp, bufH, a3s, a3d, es, ed, N, 192, 384);
    }
    {
        long total = (long)N * 384 / 8;
        aggregate_fused<64><<<(total + 255) / 256, 256, 0, stream>>>(bufH, es, ed, offsets,
                                                                     ssrc, bufA, N);
    }

    // sum-pool -> normalize -> dense
    hipMemsetAsync(g, 0, 384 * 4, stream);
    pool_kernel<<<256, 256, 0, stream>>>(bufA, g, N);
    final_kernel<<<1, 384, 0, stream>>>(g, Wd, bd, outp);
}

// Round 10
// 570.598 us; speedup vs baseline: 2.0798x; 1.1206x over previous
//
#include <hip/hip_runtime.h>
#include <hip/hip_bf16.h>

// GAT 3-layer: N=50000 nodes, E=800000 edges, H=6 heads.
// R1-R8: tiled GEMMs, CSR dst-centric softmax+aggregate (fused, atomic-free),
//        bf16 h storage, parallel scan. f32-VALU GEMM plateaued at ~54% VALU:
//        LDS-BW bound (64 ds_read_b128 per wave-tile > VALU demand).
// R9: layers 2/3 transform -> MFMA split-bf16 (3-pass ah*bh + al*bh + ah*bl,
//     ~2^-16 relative error, far below the 2^-8 h-rounding). A/B operands are
//     produced PRE-PACKED in mfma fragment layout (aggregate writes Ah/Al,
//     repack_w_mfma writes Bh/Bl); zero-padded tiles for M/N tails.

#define HHEADS 6

typedef __attribute__((ext_vector_type(8))) short bf16x8;   // 8 bf16 = 4 VGPR
typedef __attribute__((ext_vector_type(4))) float f32x4;    // mfma C/D

__device__ __forceinline__ float bfl(unsigned u) { return __uint_as_float(u << 16); }
__device__ __forceinline__ float bfh(unsigned u) { return __uint_as_float(u & 0xffff0000u); }
__device__ __forceinline__ unsigned short f2bf(float v) {  // RNE f32->bf16
    unsigned u = __float_as_uint(v);
    return (unsigned short)((u + 0x7fffu + ((u >> 16) & 1u)) >> 16);
}
__device__ __forceinline__ float bf2f(unsigned short h) {
    return __uint_as_float((unsigned)h << 16);
}

// ---------------- CSR build ----------------
__global__ void hist_kernel(const int* __restrict__ dst, int* __restrict__ count, int E) {
    int e = blockIdx.x * blockDim.x + threadIdx.x;
    if (e >= E) return;
    atomicAdd(&count[dst[e]], 1);
}

__global__ void scan_block(const int* __restrict__ count, int* __restrict__ offsets,
                           int* __restrict__ bsum, int n) {
    __shared__ int s[1024];
    int i = blockIdx.x * 1024 + threadIdx.x;
    int v = (i < n) ? count[i] : 0;
    s[threadIdx.x] = v;
    __syncthreads();
    for (int off = 1; off < 1024; off <<= 1) {
        int t = (threadIdx.x >= (unsigned)off) ? s[threadIdx.x - off] : 0;
        __syncthreads();
        s[threadIdx.x] += t;
        __syncthreads();
    }
    if (i < n) offsets[i] = s[threadIdx.x] - v;
    if (threadIdx.x == 1023) bsum[blockIdx.x] = s[1023];
}

__global__ void scan_tops(int* __restrict__ bsum, int nb) {
    __shared__ int s[64];
    int t = threadIdx.x;
    int v = (t < nb) ? bsum[t] : 0;
    s[t] = v;
    __syncthreads();
    for (int off = 1; off < 64; off <<= 1) {
        int tmp = (t >= off) ? s[t - off] : 0;
        __syncthreads();
        s[t] += tmp;
        __syncthreads();
    }
    if (t < nb) bsum[t] = s[t] - v;
}

__global__ void scan_add(int* __restrict__ offsets, const int* __restrict__ bsum, int n,
                         int total) {
    int i = blockIdx.x * 1024 + threadIdx.x;
    if (i < n) offsets[i] += bsum[blockIdx.x];
    if (i == 0) offsets[n] = total;
}

__global__ void scatter_kernel(const int* __restrict__ src, const int* __restrict__ dst,
                               const int* __restrict__ offsets, int* __restrict__ cursor,
                               int* __restrict__ ssrc, int E) {
    int e = blockIdx.x * blockDim.x + threadIdx.x;
    if (e >= E) return;
    int d = dst[e];
    int pos = offsets[d] + atomicAdd(&cursor[d], 1);
    ssrc[pos] = src[e];
}

// ---------------- weight repacks ----------------
// f32 [K][HF] for the layer-1 VALU gemm
__global__ void repack_w(const float* __restrict__ W, float* __restrict__ Wp, int FIN, int F) {
    int HF = HHEADS * F;
    int i = blockIdx.x * blockDim.x + threadIdx.x;
    if (i >= FIN * HF) return;
    int k = i / HF, c = i % HF;
    int hd = c / F, f = c % F;
    Wp[i] = W[(hd * FIN + k) * F + f];
}

// split-bf16 pack in MFMA B-fragment layout (B^T: lane n=..&15, k contiguous):
// elem[((nt16*NKT + kt)*64 + ((n&15)|(((k>>3)&3)<<4)))*8 + (k&7)]
__global__ void repack_w_mfma(const float* __restrict__ W, unsigned short* __restrict__ bh,
                              unsigned short* __restrict__ bl, int FIN, int F, int NPAD) {
    int i = blockIdx.x * blockDim.x + threadIdx.x;
    if (i >= FIN * NPAD) return;
    int k = i / NPAD, n = i % NPAD;
    int NKT = FIN / 32;
    int HF = HHEADS * F;
    float w = 0.f;
    if (n < HF) {
        int hd = n / F, f = n % F;
        w = W[(hd * FIN + k) * F + f];
    }
    unsigned short h = f2bf(w);
    unsigned short l = f2bf(w - bf2f(h));
    size_t e = ((size_t)((n >> 4) * NKT + (k >> 5)) * 64 + ((n & 15) | (((k >> 3) & 3) << 4))) * 8 +
               (k & 7);
    bh[e] = h;
    bl[e] = l;
}

// ---------------- small GEMM (layer 1, K=11): 64x64, 4x4 micro-tile ----------------
template <int BM, int BN, int BK>
__global__ __launch_bounds__(256) void gemm_small(const float* __restrict__ A,
                                                  const float* __restrict__ B,
                                                  __hip_bfloat16* __restrict__ C, int M,
                                                  int K, int N) {
    __shared__ float As[BK][BM + 4];
    __shared__ float Bs[BK][BN];
    int tid = threadIdx.x;
    int tx = tid % 16, ty = tid / 16;
    int m0 = blockIdx.y * BM, n0 = blockIdx.x * BN;
    float acc[4][4] = {};
    for (int kk0 = 0; kk0 < K; kk0 += BK) {
#pragma unroll
        for (int i = 0; i < (BM * BK) / 256; ++i) {
            int idx = tid + i * 256;
            int m = idx / BK, k = idx % BK;
            float v = 0.f;
            if (m0 + m < M && kk0 + k < K) v = A[(size_t)(m0 + m) * K + kk0 + k];
            As[k][m] = v;
        }
#pragma unroll
        for (int i = 0; i < (BK * BN) / 1024; ++i) {
            int idx = tid + i * 256;
            int k = idx / (BN / 4), n4 = idx % (BN / 4);
            float4 v = make_float4(0.f, 0.f, 0.f, 0.f);
            if (kk0 + k < K && n0 + n4 * 4 < N)
                v = *(const float4*)&B[(size_t)(kk0 + k) * N + n0 + n4 * 4];
            *(float4*)&Bs[k][n4 * 4] = v;
        }
        __syncthreads();
#pragma unroll
        for (int k = 0; k < BK; ++k) {
            float4 av = *(const float4*)&As[k][ty * 4];
            float4 bv = *(const float4*)&Bs[k][tx * 4];
            float a[4] = {av.x, av.y, av.z, av.w};
            float b[4] = {bv.x, bv.y, bv.z, bv.w};
#pragma unroll
            for (int i = 0; i < 4; ++i)
#pragma unroll
                for (int j = 0; j < 4; ++j) acc[i][j] += a[i] * b[j];
        }
        __syncthreads();
    }
#pragma unroll
    for (int i = 0; i < 4; ++i) {
        int m = m0 + ty * 4 + i;
        if (m < M && n0 + tx * 4 < N) {
            __hip_bfloat16 tmp[4];
#pragma unroll
            for (int j = 0; j < 4; ++j) tmp[j] = __float2bfloat16(acc[i][j]);
            *(uint2*)&C[(size_t)m * N + n0 + tx * 4] = *(uint2*)tmp;
        }
    }
}

// es[n,hd] for layer 1; block = HF threads, one node per block.
template <int F>
__global__ void attn_terms(const __hip_bfloat16* __restrict__ h, const float* __restrict__ as_,
                           const float* __restrict__ ad_, float* __restrict__ es,
                           float* __restrict__ ed) {
    constexpr int HF = HHEADS * F;
    int node = blockIdx.x;
    int t = threadIdx.x;
    float v = __bfloat162float(h[(size_t)node * HF + t]);
    float s = v * as_[t];
    float d = v * ad_[t];
#pragma unroll
    for (int off = F / 2; off > 0; off >>= 1) {
        s += __shfl_down(s, off, F);
        d += __shfl_down(d, off, F);
    }
    if ((t & (F - 1)) == 0) {
        int hd = t / F;
        es[node * HHEADS + hd] = s;
        ed[node * HHEADS + hd] = d;
    }
}

// ---------------- MFMA split-bf16 GEMM + fused attn (layers 2/3) ----------------
// C[M,N] = A@B via 3-pass split bf16 (ah*bh + al*bh + ah*bl). 128x128 tile,
// 4 waves in 2x2 (each 64x64 = 4x4 mfma positions of 16x16x32).
// A/B read pre-packed in fragment layout: per (tile16, kt): 64 lanes x 8 bf16.
// Frag layouts (m89/m97-verified): A: lane m=lane&15, k=quad*8+j;
// B: lane n=lane&15, k=quad*8+j; C/D: col=lane&15, row=quad*4+reg.
template <int K, int NREAL, int NPAD, int F>
__global__ __launch_bounds__(256) void gemm_attn_mfma(
    const unsigned short* __restrict__ Ah, const unsigned short* __restrict__ Al,
    const unsigned short* __restrict__ Bh, const unsigned short* __restrict__ Bl,
    __hip_bfloat16* __restrict__ C, const float* __restrict__ as_,
    const float* __restrict__ ad_, float* __restrict__ es, float* __restrict__ ed, int M) {
    constexpr int NKT = K / 32;
    __shared__ unsigned short sAh[4096], sAl[4096], sBh[4096], sBl[4096];  // 8 tiles each
    int tid = threadIdx.x;
    int lane = tid & 63, wave = tid >> 6;
    int wrow = wave >> 1, wcol = wave & 1;
    int quad = lane >> 4, c16 = lane & 15;
    int m0 = blockIdx.y * 128, n0 = blockIdx.x * 128;
    int bt16 = m0 >> 4, bn16 = n0 >> 4;

    f32x4 acc[4][4] = {};
    for (int kt = 0; kt < NKT; ++kt) {
        // stage 8 A-tiles + 8 B-tiles (h+l planes), 1024 B per tile per plane
#pragma unroll
        for (int rep = 0; rep < 2; ++rep) {
            int chunk = tid + rep * 256;  // 0..511
            int tile = chunk >> 6, e8 = chunk & 63;
            size_t aoff = ((size_t)((bt16 + tile) * NKT + kt) * 64 + e8) * 8;
            size_t boff = ((size_t)((bn16 + tile) * NKT + kt) * 64 + e8) * 8;
            *(uint4*)&sAh[chunk * 8] = *(const uint4*)&Ah[aoff];
            *(uint4*)&sAl[chunk * 8] = *(const uint4*)&Al[aoff];
            *(uint4*)&sBh[chunk * 8] = *(const uint4*)&Bh[boff];
            *(uint4*)&sBl[chunk * 8] = *(const uint4*)&Bl[boff];
        }
        __syncthreads();
        bf16x8 fah[4], fal[4], fbh[4], fbl[4];
#pragma unroll
        for (int i = 0; i < 4; ++i) {
            fah[i] = *(const bf16x8*)&sAh[(wrow * 4 + i) * 512 + lane * 8];
            fal[i] = *(const bf16x8*)&sAl[(wrow * 4 + i) * 512 + lane * 8];
            fbh[i] = *(const bf16x8*)&sBh[(wcol * 4 + i) * 512 + lane * 8];
            fbl[i] = *(const bf16x8*)&sBl[(wcol * 4 + i) * 512 + lane * 8];
        }
#pragma unroll
        for (int i = 0; i < 4; ++i)
#pragma unroll
            for (int j = 0; j < 4; ++j) {
                acc[i][j] = __builtin_amdgcn_mfma_f32_16x16x32_bf16(fah[i], fbh[j], acc[i][j],
                                                                    0, 0, 0);
                acc[i][j] = __builtin_amdgcn_mfma_f32_16x16x32_bf16(fal[i], fbh[j], acc[i][j],
                                                                    0, 0, 0);
                acc[i][j] = __builtin_amdgcn_mfma_f32_16x16x32_bf16(fah[i], fbl[j], acc[i][j],
                                                                    0, 0, 0);
            }
        __syncthreads();
    }

    // epilogue: C bf16 write + es/ed segmented reduction from f32 acc
    float asv[4], adv[4];
#pragma unroll
    for (int j = 0; j < 4; ++j) {
        int col = n0 + wcol * 64 + j * 16 + c16;
        bool ok = col < NREAL;
        asv[j] = ok ? as_[col] : 0.f;
        adv[j] = ok ? ad_[col] : 0.f;
    }
#pragma unroll
    for (int i = 0; i < 4; ++i) {
#pragma unroll
        for (int r = 0; r < 4; ++r) {
            int m = m0 + wrow * 64 + i * 16 + quad * 4 + r;
            bool mok = m < M;
            if (mok) {
#pragma unroll
                for (int j = 0; j < 4; ++j) {
                    int col = n0 + wcol * 64 + j * 16 + c16;
                    if (col < NREAL) C[(size_t)m * NREAL + col] = __float2bfloat16(acc[i][j][r]);
                }
            }
            if (F == 64) {
                float ps = acc[i][0][r] * asv[0] + acc[i][1][r] * asv[1] +
                           acc[i][2][r] * asv[2] + acc[i][3][r] * asv[3];
                float pd = acc[i][0][r] * adv[0] + acc[i][1][r] * adv[1] +
                           acc[i][2][r] * adv[2] + acc[i][3][r] * adv[3];
#pragma unroll
                for (int off = 8; off > 0; off >>= 1) {
                    ps += __shfl_down(ps, off, 16);
                    pd += __shfl_down(pd, off, 16);
                }
                if (mok && c16 == 0) {
                    int hd = (n0 + wcol * 64) / 64;
                    es[(size_t)m * HHEADS + hd] = ps;
                    ed[(size_t)m * HHEADS + hd] = pd;
                }
            } else {  // F == 32: two heads per wave-column
                float psA = acc[i][0][r] * asv[0] + acc[i][1][r] * asv[1];
                float pdA = acc[i][0][r] * adv[0] + acc[i][1][r] * adv[1];
                float psB = acc[i][2][r] * asv[2] + acc[i][3][r] * asv[3];
                float pdB = acc[i][2][r] * adv[2] + acc[i][3][r] * adv[3];
#pragma unroll
                for (int off = 8; off > 0; off >>= 1) {
                    psA += __shfl_down(psA, off, 16);
                    pdA += __shfl_down(pdA, off, 16);
                    psB += __shfl_down(psB, off, 16);
                    pdB += __shfl_down(pdB, off, 16);
                }
                if (mok && c16 == 0) {
                    int colbase = n0 + wcol * 64;
                    if (colbase < NREAL) {
                        int hd = colbase / 32;
                        es[(size_t)m * HHEADS + hd] = psA;
                        ed[(size_t)m * HHEADS + hd] = pdA;
                        es[(size_t)m * HHEADS + hd + 1] = psB;
                        ed[(size_t)m * HHEADS + hd + 1] = pdB;
                    }
                }
            }
        }
    }
}

// ---------------- fused edge softmax + aggregate (flash-style) ----------------
// PACK=true: write split-bf16 A-operand planes in MFMA fragment layout (feeds
// the next layer's MFMA GEMM). PACK=false: plain f32 (layer 3 -> pool).
template <int F, bool PACK>
__global__ void aggregate_fused(const __hip_bfloat16* __restrict__ h,
                                const float* __restrict__ es, const float* __restrict__ ed,
                                const int* __restrict__ offsets, const int* __restrict__ ssrc,
                                unsigned short* __restrict__ oh, unsigned short* __restrict__ ol,
                                float* __restrict__ outf, int n) {
    constexpr int HF = HHEADS * F;
    constexpr int C8 = HF / 8;
    int tid = blockIdx.x * blockDim.x + threadIdx.x;
    if (tid >= n * C8) return;
    int node = tid / C8, q = tid % C8;
    int c = q * 8, hd = c / F;
    int a = offsets[node], b = offsets[node + 1];
    float edv = ed[node * HHEADS + hd];
    float m = -1e30f, l = 0.f;
    float acc[8] = {};
    for (int j = a; j < b; ++j) {
        int s = ssrc[j];
        float v = es[s * HHEADS + hd] + edv;
        v = v > 0.f ? v : 0.2f * v;  // leaky relu 0.2
        float mn = fmaxf(m, v);
        float r = expf(m - mn);
        float w = expf(v - mn);
        uint4 hv = *(const uint4*)&h[(size_t)s * HF + c];
        l = l * r + w;
        acc[0] = acc[0] * r + w * bfl(hv.x);
        acc[1] = acc[1] * r + w * bfh(hv.x);
        acc[2] = acc[2] * r + w * bfl(hv.y);
        acc[3] = acc[3] * r + w * bfh(hv.y);
        acc[4] = acc[4] * r + w * bfl(hv.z);
        acc[5] = acc[5] * r + w * bfh(hv.z);
        acc[6] = acc[6] * r + w * bfl(hv.w);
        acc[7] = acc[7] * r + w * bfh(hv.w);
        m = mn;
    }
    float invd = 1.0f / (l + 1e-16f);
    float res[8];
#pragma unroll
    for (int k = 0; k < 8; ++k) {
        float v = acc[k] * invd;
        res[k] = v > 0.f ? v : (expf(v) - 1.0f);  // elu
    }
    if (PACK) {
        constexpr int NKT = HF / 32;
        unsigned short th[8], tl[8];
#pragma unroll
        for (int k = 0; k < 8; ++k) {
            unsigned short hh = f2bf(res[k]);
            th[k] = hh;
            tl[k] = f2bf(res[k] - bf2f(hh));
        }
        int lq = (node & 15) | (((c >> 3) & 3) << 4);
        size_t base = ((size_t)((node >> 4) * NKT + (c >> 5)) * 64 + lq) * 8;
        *(uint4*)&oh[base] = *(uint4*)th;
        *(uint4*)&ol[base] = *(uint4*)tl;
    } else {
        float4 o0 = make_float4(res[0], res[1], res[2], res[3]);
        float4 o1 = make_float4(res[4], res[5], res[6], res[7]);
        *(float4*)&outf[(size_t)node * HF + c] = o0;
        *(float4*)&outf[(size_t)node * HF + c + 4] = o1;
    }
}

// ---------------- pooling + head ----------------
__global__ void pool_kernel(const float* __restrict__ out3, float* __restrict__ g, int n) {
    int b = blockIdx.x, t = threadIdx.x;
    int chunk = (n + gridDim.x - 1) / gridDim.x;
    int n0 = b * chunk, n1 = min(n, n0 + chunk);
    float a0 = 0.f, a1 = 0.f;
    for (int node = n0; node < n1; ++node) {
        a0 += out3[(size_t)node * 384 + t];
        if (t < 128) a1 += out3[(size_t)node * 384 + 256 + t];
    }
    atomicAdd(&g[t], a0);
    if (t < 128) atomicAdd(&g[256 + t], a1);
}

__global__ void final_kernel(const float* __restrict__ g, const float* __restrict__ Wd,
                             const float* __restrict__ bd, float* __restrict__ outp) {
    __shared__ float red[384];
    int t = threadIdx.x;  // blockDim = 384
    float v = g[t];
    red[t] = v * v;
    __syncthreads();
    for (int s = 192; s >= 3; s >>= 1) {
        if (t < s) red[t] += red[t + s];
        __syncthreads();
    }
    __shared__ float scale_s;
    if (t == 0) {
        float norm = sqrtf(red[0] + red[1] + red[2]);
        scale_s = 1.0f / fmaxf(norm, 1e-12f);
    }
    __syncthreads();
    float scale = scale_s;
    red[t] = v * scale * Wd[t];
    __syncthreads();
    for (int s = 192; s >= 3; s >>= 1) {
        if (t < s) red[t] += red[t + s];
        __syncthreads();
    }
    if (t == 0) outp[0] = red[0] + red[1] + red[2] + bd[0];
}

// ---------------- host side ----------------
extern "C" void kernel_launch(void* const* d_in, const int* in_sizes, int n_in, void* d_out,
                              int out_size, void* d_ws, size_t ws_size, hipStream_t stream) {
    const float* x = (const float*)d_in[0];
    const int* ei = (const int*)d_in[1];
    const float* W1 = (const float*)d_in[2];
    const float* a1s = (const float*)d_in[3];
    const float* a1d = (const float*)d_in[4];
    const float* W2 = (const float*)d_in[5];
    const float* a2s = (const float*)d_in[6];
    const float* a2d = (const float*)d_in[7];
    const float* W3 = (const float*)d_in[8];
    const float* a3s = (const float*)d_in[9];
    const float* a3d = (const float*)d_in[10];
    const float* Wd = (const float*)d_in[11];
    const float* bd = (const float*)d_in[12];
    float* outp = (float*)d_out;

    const int N = in_sizes[0] / 11;
    const int E = in_sizes[1] / 2;
    const int* src = ei;
    const int* dst = ei + E;

    // tile16 count (M=50000 -> 3125 exact; blocks pad to 3128)
    const int NT16 = ((N + 127) / 128) * 8;

    char* w = (char*)d_ws;
    size_t off = 0;
    auto A = [&](size_t bytes) {
        size_t o = off;
        off += (bytes + 255) & ~(size_t)255;
        return o;
    };
    __hip_bfloat16* bufH = (__hip_bfloat16*)(w + A((size_t)N * 384 * 2));  // h (bf16)
    float* bufA = (float*)(w + A((size_t)N * 384 * 4));                    // layer3 out (f32)
    unsigned short* apH = (unsigned short*)(w + A((size_t)NT16 * 6 * 512 * 2));  // A-pack hi
    unsigned short* apL = (unsigned short*)(w + A((size_t)NT16 * 6 * 512 * 2));  // A-pack lo
    unsigned short* b2H = (unsigned short*)(w + A((size_t)16 * 3 * 512 * 2));    // W2 pack
    unsigned short* b2L = (unsigned short*)(w + A((size_t)16 * 3 * 512 * 2));
    unsigned short* b3H = (unsigned short*)(w + A((size_t)24 * 6 * 512 * 2));    // W3 pack
    unsigned short* b3L = (unsigned short*)(w + A((size_t)24 * 6 * 512 * 2));
    float* es = (float*)(w + A((size_t)N * HHEADS * 4));
    float* ed = (float*)(w + A((size_t)N * HHEADS * 4));
    float* wp = (float*)(w + A((size_t)11 * 96 * 4));  // layer-1 f32 repack
    int* count = (int*)(w + A((size_t)(N + 1) * 4));
    int* cursor = (int*)(w + A((size_t)(N + 1) * 4));
    int* offsets = (int*)(w + A((size_t)(N + 1) * 4));
    int* bsum = (int*)(w + A(64 * 4));
    int* ssrc = (int*)(w + A((size_t)E * 4));
    float* g = (float*)(w + A(384 * 4));

    // CSR build (by dst)
    hipMemsetAsync(count, 0, (size_t)N * 4, stream);
    hipMemsetAsync(cursor, 0, (size_t)N * 4, stream);
    hist_kernel<<<(E + 255) / 256, 256, 0, stream>>>(dst, count, E);
    int nb = (N + 1023) / 1024;
    scan_block<<<nb, 1024, 0, stream>>>(count, offsets, bsum, N);
    scan_tops<<<1, 64, 0, stream>>>(bsum, nb);
    scan_add<<<nb, 1023 + 1, 0, stream>>>(offsets, bsum, N, E);
    scatter_kernel<<<(E + 255) / 256, 256, 0, stream>>>(src, dst, offsets, cursor, ssrc, E);

    // weight packs
    repack_w<<<(11 * 96 + 255) / 256, 256, 0, stream>>>(W1, wp, 11, 16);
    repack_w_mfma<<<(96 * 256 + 255) / 256, 256, 0, stream>>>(W2, b2H, b2L, 96, 32, 256);
    repack_w_mfma<<<(192 * 384 + 255) / 256, 256, 0, stream>>>(W3, b3H, b3L, 192, 64, 384);

    // zero A-pack pad tiles (tile16 = 3125..3127) for both layouts (NKT=3 and 6)
    const int t16v = N / 16;  // 3125 (N % 16 == 0)
    const int padT = NT16 - t16v;  // 3
    hipMemsetAsync(apH + (size_t)t16v * 3 * 512, 0, (size_t)padT * 3 * 512 * 2, stream);
    hipMemsetAsync(apL + (size_t)t16v * 3 * 512, 0, (size_t)padT * 3 * 512 * 2, stream);
    hipMemsetAsync(apH + (size_t)t16v * 6 * 512, 0, (size_t)padT * 6 * 512 * 2, stream);
    hipMemsetAsync(apL + (size_t)t16v * 6 * 512, 0, (size_t)padT * 6 * 512 * 2, stream);

    // ---- layer 1 (FIN=11, F=16) ----
    {
        dim3 grid((96 + 63) / 64, (N + 63) / 64);
        gemm_small<64, 64, 32><<<grid, 256, 0, stream>>>(x, wp, bufH, N, 11, 96);
    }
    attn_terms<16><<<N, 96, 0, stream>>>(bufH, a1s, a1d, es, ed);
    {
        long total = (long)N * 96 / 8;
        aggregate_fused<16, true><<<(total + 255) / 256, 256, 0, stream>>>(
            bufH, es, ed, offsets, ssrc, apH, apL, nullptr, N);
    }

    // ---- layer 2 (K=96, N=192 pad 256, F=32) ----
    {
        dim3 grid(256 / 128, (N + 127) / 128);
        gemm_attn_mfma<96, 192, 256, 32><<<grid, 256, 0, stream>>>(apH, apL, b2H, b2L, bufH,
                                                                   a2s, a2d, es, ed, N);
    }
    {
        long total = (long)N * 192 / 8;
        aggregate_fused<32, true><<<(total + 255) / 256, 256, 0, stream>>>(
            bufH, es, ed, offsets, ssrc, apH, apL, nullptr, N);
    }

    // ---- layer 3 (K=192, N=384, F=64) ----
    {
        dim3 grid(384 / 128, (N + 127) / 128);
        gemm_attn_mfma<192, 384, 384, 64><<<grid, 256, 0, stream>>>(apH, apL, b3H, b3L, bufH,
                                                                    a3s, a3d, es, ed, N);
    }
    {
        long total = (long)N * 384 / 8;
        aggregate_fused<64, false><<<(total + 255) / 256, 256, 0, stream>>>(
            bufH, es, ed, offsets, ssrc, nullptr, nullptr, bufA, N);
    }

    // sum-pool -> normalize -> dense
    hipMemsetAsync(g, 0, 384 * 4, stream);
    pool_kernel<<<256, 256, 0, stream>>>(bufA, g, N);
    final_kernel<<<1, 384, 0, stream>>>(g, Wd, bd, outp);
}